// Round 12
// baseline (93.282 us; speedup 1.0000x reference)
//
#include <hip/hip_runtime.h>
#include <stdint.h>

// ---------------------------------------------------------------------------
// AttentionBlock: GroupNorm(32) -> qkv 1x1 -> 8-head attention (T=1024,ch=64)
//                 -> proj 1x1 + residual.  B=8, C=512, T=1024. fp32 I/O,
//                 bf16 MFMA internally.  5 kernels:
//   prep   : gn group stats (256 blk) + weight fp32->bf16 cvt (512 blk)
//   gn_norm: normalize+affine -> bf16 xnT[b][t][c] (t-major, LDS transpose)
//   gemmQKV: fused, 3 block types: Q = D[t][o] -> qbuf[b][t][512];
//            K = D[ck][t] (V-orientation) -> kbuf frag-tiles, s16x4 stores;
//            V = D[t][o'] -> vbuf frag-tiles, s16x4 stores.
//   attn   : barrier-free flash, 1024 blk x 4 waves x 16t (nt=1/wave ->
//            4 waves/SIMD); K/V frags = coalesced 1KB b128 L2 loads;
//            exp2 direct (no max: |s|<~10, softmax shift-invariant);
//            l per-lane, reduced once at end.
//   proj   : D[o][t] = Wp x att + bias + x -> d_out; LDS-transposed epilogue.
// Frag-tile layout (1KB): addr = tile*512 + lane*8 + j; A/B share slot->k map
//   so the HW k-permutation cancels.
// Lessons: R4 spills; R5 LDS>64K; R7 split-s traffic; R8 strided V reads;
//   R9/R10 scattered 2B stores; R11 attn latency-bound at 2 waves/SIMD ->
//   t-split x2 (this round).
// ---------------------------------------------------------------------------

typedef float  f32x4  __attribute__((ext_vector_type(4)));
typedef short  s16x4  __attribute__((ext_vector_type(4)));
typedef short  s16x8  __attribute__((ext_vector_type(8)));
typedef __bf16 bf16x8 __attribute__((ext_vector_type(8)));

#define QK_SCALE 0.4246609f   // sqrt(0.125 * log2(e))

__device__ __forceinline__ f32x4 mfma_bf16_16x16x32(s16x8 a, s16x8 b, f32x4 c){
  return __builtin_amdgcn_mfma_f32_16x16x32_bf16(
      __builtin_bit_cast(bf16x8, a), __builtin_bit_cast(bf16x8, b), c, 0, 0, 0);
}

__device__ __forceinline__ short f2bf(float v){
  return __builtin_bit_cast(short, static_cast<__bf16>(v));
}

// async global->LDS, 16B per lane; dest = firstlane-base + lane*16 (linear)
__device__ __forceinline__ void gload16(const void* g, void* l){
  __builtin_amdgcn_global_load_lds(
      (const __attribute__((address_space(1))) void*)g,
      (__attribute__((address_space(3))) void*)l, 16, 0, 0);
}

// ---------------------------------------------------------------------------
// prep: blocks 0..255 = GroupNorm stats per (b,g); blocks 256..767 = weight cvt
__global__ __launch_bounds__(256) void prep_kernel(const float* __restrict__ x,
    float2* __restrict__ stats, const float* __restrict__ qkv_w,
    const float* __restrict__ proj_w, short* __restrict__ qwb,
    short* __restrict__ pwb){
  if (blockIdx.x < 256){
    __shared__ float ss[256], sq[256];
    const int bg = blockIdx.x;
    const float4* base = (const float4*)(x + (size_t)bg * 16384);
    float s = 0.f, q = 0.f;
    #pragma unroll
    for (int i = 0; i < 16; ++i){
      float4 v = base[threadIdx.x + i*256];
      s += v.x + v.y + v.z + v.w;
      q += v.x*v.x + v.y*v.y + v.z*v.z + v.w*v.w;
    }
    ss[threadIdx.x] = s; sq[threadIdx.x] = q;
    __syncthreads();
    for (int off = 128; off > 0; off >>= 1){
      if (threadIdx.x < off){ ss[threadIdx.x] += ss[threadIdx.x+off];
                              sq[threadIdx.x] += sq[threadIdx.x+off]; }
      __syncthreads();
    }
    if (threadIdx.x == 0){
      float mu  = ss[0] * (1.f/16384.f);
      float var = sq[0] * (1.f/16384.f) - mu*mu;   // biased (matches jnp.var)
      stats[bg] = make_float2(mu, rsqrtf(var + 1e-5f));
    }
  } else {
    const int i = (blockIdx.x - 256)*256 + threadIdx.x;   // 0..131071
    const float* in; short* out; float s;
    if (i < 98304){
      in = qkv_w + (size_t)i*8; out = qwb + (size_t)i*8;
      s = (((i >> 6) % 192) < 128) ? QK_SCALE : 1.f;     // q,k rows pre-scaled
    } else {
      const int j = i - 98304;
      in = proj_w + (size_t)j*8; out = pwb + (size_t)j*8;
      s = 1.f;
    }
    const float4* p = (const float4*)in;
    float4 a = p[0], b = p[1];
    s16x8 o;
    o[0]=f2bf(a.x*s); o[1]=f2bf(a.y*s); o[2]=f2bf(a.z*s); o[3]=f2bf(a.w*s);
    o[4]=f2bf(b.x*s); o[5]=f2bf(b.y*s); o[6]=f2bf(b.z*s); o[7]=f2bf(b.w*s);
    *(s16x8*)out = o;
  }
}

// normalize + affine -> bf16 xnT[b][t][c] (transposed via LDS tile)
__global__ __launch_bounds__(256) void gn_norm_t_kernel(const float* __restrict__ x,
    const float* __restrict__ w, const float* __restrict__ bia,
    const float2* __restrict__ stats, short* __restrict__ xnT){
  const int t0 = blockIdx.x * 64, b = blockIdx.y;
  const int tid = threadIdx.x;
  __shared__ short L[64*68];                 // [c][t] pad->68
  const float* xb = x   + (size_t)b * 524288;
  short*       ob = xnT + (size_t)b * 524288;
  for (int cc = 0; cc < 8; ++cc){
    #pragma unroll
    for (int i = 0; i < 4; ++i){
      const int f  = tid + i*256;            // 0..1023
      const int cl = f >> 4, t4 = (f & 15) * 4;
      const int ch = cc*64 + cl;
      const float2 st = stats[b*32 + (ch >> 4)];
      const float sc = st.y * w[ch];
      const float sh = bia[ch] - st.x * sc;
      float4 v = *(const float4*)(xb + (size_t)ch*1024 + t0 + t4);
      s16x4 o;
      o[0]=f2bf(v.x*sc+sh); o[1]=f2bf(v.y*sc+sh); o[2]=f2bf(v.z*sc+sh); o[3]=f2bf(v.w*sc+sh);
      *(s16x4*)&L[cl*68 + t4] = o;
    }
    __syncthreads();
    #pragma unroll
    for (int i = 0; i < 2; ++i){
      const int g  = tid + i*256;            // 0..511
      const int tl = g >> 3, c8 = g & 7;
      s16x8 o;
      #pragma unroll
      for (int j = 0; j < 8; ++j) o[j] = L[(c8*8 + j)*68 + tl];
      *(s16x8*)(ob + (size_t)(t0 + tl)*512 + cc*64 + c8*8) = o;
    }
    __syncthreads();
  }
}

// ---------------------------------------------------------------------------
// Unified K=512 GEMM, 128xNB tile, BK=32, 4 waves (2x2).
// Staging: global_load_lds w=16 into linear [row][32] tiles; XOR swizzle
// slot = lb ^ ((row>>1)&3) on reads, source chunk (c&3)^((c>>3)&3) on stage.
// MODE 0 (NB=128, fused QKV), block type by z:
//   z<4 : Q: A=xnT t-rows (m0=y*128), B=Wq o-rows (n0=z*128)   -> qbuf[t][512]
//   4-7 : K: A=Wk ck-rows (m0=(z-4)*128), B=xnT t-rows (n0=y*128)
//         -> kbuf frag-tiles, r-contiguous s16x4 (512B/instr segments)
//   8-11: V: A=xnT t-rows (m0=y*128), B=Wv o'-rows (n0=1024+(z-8)*128)
//         -> vbuf frag-tiles, s16x4 stores
// MODE 2 (NB=64): A=Wp o-rows, B=attT t-rows -> f32 out via LDS-transposed
//   epilogue: 256B-coalesced float4 resid-add/store.
template<int MODE, int NB>
__global__ __launch_bounds__(256) void gemm_k512(const short* __restrict__ W,
    const short* __restrict__ act, const float* __restrict__ bias,
    const float* __restrict__ resid, void* __restrict__ outp,
    void* __restrict__ outp2, void* __restrict__ outp3){
  constexpr int NSF = NB / 32;      // n-frags per wave
  constexpr int SMEM_BYTES = (MODE == 2) ? 34816 : 32768;
  const int b  = blockIdx.x;
  const int tid  = threadIdx.x;
  const int lane = tid & 63, w = tid >> 6;
  const int wm = w >> 1, wn = w & 1;
  const int lm = lane & 15, lb = lane >> 4;
  const int xr = (lm >> 1) & 3;     // row-swizzle term for frag reads

  int part, m0, n0;
  if constexpr (MODE == 0){
    const int z = blockIdx.z;
    part = (z >= 8) ? 2 : (z >= 4 ? 1 : 0);
    m0 = (part == 1) ? (z - 4)*128 : blockIdx.y*128;
    n0 = (part == 0) ? z*128 : (part == 1 ? blockIdx.y*128 : 1024 + (z - 8)*128);
  } else {
    part = 0; m0 = blockIdx.y*128; n0 = blockIdx.z*NB;
  }

  __shared__ __align__(16) char smem[SMEM_BYTES];
  short* Asb = (short*)smem;                 // [2][128*32]
  short* Bsb = (short*)(smem + 16384);       // [2][NB*32]

  const short* actb = act + (size_t)b * 524288;

  auto arow = [&](int r) -> const short* {
    if constexpr (MODE == 0){
      if (part == 1){
        const int m = m0 + r;
        return W + (size_t)(192*(m>>6) + 64 + (m&63)) * 512;
      }
      return actb + (size_t)(m0 + r) * 512;
    } else {
      return W + (size_t)(m0 + r) * 512;
    }
  };
  auto brow = [&](int r) -> const short* {
    if constexpr (MODE == 0){
      if (part == 1) return actb + (size_t)(n0 + r) * 512;
      const int o = n0 + r;
      return W + (size_t)(192*((o>>6)&7) + (o>>9)*64 + (o&63)) * 512;
    } else {
      return actb + (size_t)(n0 + r) * 512;
    }
  };

  // stage K-tile t into buf: async gload_lds; source chunk pre-swizzled
  auto stage = [&](int t, int buf){
    const int k0 = t * 32;
    #pragma unroll
    for (int i = 0; i < 2; ++i){
      const int c = tid + i*256;
      const int r = c >> 2, sj = (c & 3) ^ ((c >> 3) & 3);
      gload16(arow(r) + k0 + sj*8, Asb + buf*4096 + (c>>2)*32 + (c&3)*8);
    }
    #pragma unroll
    for (int i = 0; i < NB/64; ++i){
      const int c = tid + i*256;
      const int r = c >> 2, sj = (c & 3) ^ ((c >> 3) & 3);
      gload16(brow(r) + k0 + sj*8, Bsb + buf*(NB*32) + (c>>2)*32 + (c&3)*8);
    }
  };

  f32x4 acc[4][NSF] = {};
  stage(0, 0);

  for (int t = 0; t < 16; ++t){
    __syncthreads();                 // waits vmcnt(0) for prior stage
    if (t + 1 < 16) stage(t + 1, (t + 1) & 1);
    const int buf = t & 1;

    s16x8 af[4], bfr[NSF];
    #pragma unroll
    for (int ms = 0; ms < 4; ++ms){
      const int row = wm*64 + ms*16 + lm;
      af[ms] = *(const s16x8*)(Asb + buf*4096 + row*32 + ((lb ^ xr) << 3));
    }
    #pragma unroll
    for (int ns = 0; ns < NSF; ++ns){
      const int row = wn*(NB/2) + ns*16 + lm;
      bfr[ns] = *(const s16x8*)(Bsb + buf*(NB*32) + row*32 + ((lb ^ xr) << 3));
    }
    #pragma unroll
    for (int ns = 0; ns < NSF; ++ns)
      #pragma unroll
      for (int ms = 0; ms < 4; ++ms)
        acc[ms][ns] = mfma_bf16_16x16x32(af[ms], bfr[ns], acc[ms][ns]);
  }

  // C/D: col = lane&15, row = 4*(lane>>4) + reg   (m89)
  const int mo = m0 + wm*64, no = n0 + wn*(NB/2);
  if constexpr (MODE == 0){
    if (part == 0){
      short* qout = (short*)outp + (size_t)b * 524288;     // [t][512]
      float bn[NSF];
      #pragma unroll
      for (int ns = 0; ns < NSF; ++ns){
        const int o = no + ns*16 + lm;
        bn[ns] = QK_SCALE * bias[192*((o>>6)&7) + (o&63)];
      }
      #pragma unroll
      for (int ms = 0; ms < 4; ++ms)
        #pragma unroll
        for (int ns = 0; ns < NSF; ++ns)
          #pragma unroll
          for (int r = 0; r < 4; ++r){
            const int m = mo + ms*16 + 4*lb + r;
            const int n = no + ns*16 + lm;
            qout[(size_t)m*512 + n] = f2bf(acc[ms][ns][r] + bn[ns]);
          }
    } else if (part == 1){
      // K in D[ck][t] orientation: m = channel, n = s; r-contiguous tiles.
      short* kout = (short*)outp2 + (size_t)b * 524288;    // frag tiles
      const int hh = m0/64 + wm;                           // m>>6, wave-uniform
      float bm[16];
      #pragma unroll
      for (int ms = 0; ms < 4; ++ms)
        #pragma unroll
        for (int r = 0; r < 4; ++r){
          const int m = mo + ms*16 + 4*lb + r;
          bm[ms*4+r] = QK_SCALE * bias[192*(m>>6) + 64 + (m&63)];
        }
      #pragma unroll
      for (int ms = 0; ms < 4; ++ms)
        #pragma unroll
        for (int ns = 0; ns < NSF; ++ns){
          const int n = no + ns*16 + lm;                   // s
          const size_t a = ((size_t)hh*128 + (n>>4)*2 + (ms>>1))*512
                         + (((ms*2 + (lb>>1)) & 3)*16 + (n&15))*8 + 4*(lb&1);
          s16x4 o;
          #pragma unroll
          for (int r = 0; r < 4; ++r) o[r] = f2bf(acc[ms][ns][r] + bm[ms*4+r]);
          *(s16x4*)(kout + a) = o;
        }
    } else {
      short* vout = (short*)outp3 + (size_t)b * 524288;    // frag tiles
      float bn[NSF];
      #pragma unroll
      for (int ns = 0; ns < NSF; ++ns){
        const int o = no + ns*16 + lm;
        bn[ns] = bias[192*((o>>6)&7) + (o>>9)*64 + (o&63)];
      }
      #pragma unroll
      for (int ms = 0; ms < 4; ++ms)
        #pragma unroll
        for (int ns = 0; ns < NSF; ++ns){
          const int m = mo + ms*16 + 4*lb;                 // r=0 row; s = m+r
          const int n = no + ns*16 + lm;
          const int h = (n >> 6) & 7, c = n & 63;
          const size_t a = ((size_t)h*128 + (c>>4)*32 + (m>>5))*512
                         + (((m>>2)&3)*16 + (c&15))*8 + ((m>>4)&1)*4;
          s16x4 o;
          #pragma unroll
          for (int r = 0; r < 4; ++r) o[r] = f2bf(acc[ms][ns][r] + bn[ns]);
          *(s16x4*)(vout + a) = o;
        }
    }
  } else {
    // proj: LDS-transposed epilogue -> coalesced float4 resid-add/store
    __syncthreads();                          // staging reads done
    float* Lf = (float*)smem;                 // [128][68] f32
    #pragma unroll
    for (int ms = 0; ms < 4; ++ms)
      #pragma unroll
      for (int ns = 0; ns < NSF; ++ns)
        #pragma unroll
        for (int r = 0; r < 4; ++r)
          Lf[(wm*64 + ms*16 + 4*lb + r)*68 + wn*32 + ns*16 + lm] = acc[ms][ns][r];
    __syncthreads();
    float* out = (float*)outp + (size_t)b * 524288;
    const float* xr2 = resid + (size_t)b * 524288;
    #pragma unroll
    for (int p = 0; p < 8; ++p){
      const int row = p*16 + (tid >> 4);
      const int c4  = (tid & 15) * 4;
      float4 v = *(const float4*)&Lf[row*68 + c4];
      const float bs = bias[m0 + row];
      const size_t off = (size_t)(m0 + row)*1024 + n0 + c4;
      float4 rv = *(const float4*)(xr2 + off);
      float4 ov = make_float4(v.x+bs+rv.x, v.y+bs+rv.y, v.z+bs+rv.z, v.w+bs+rv.w);
      *(float4*)(out + off) = ov;
    }
  }
}

// ---------------------------------------------------------------------------
// Attention v10: barrier-free, t-split x2 vs R9. 1024 blocks x 256 thr;
// bid = bh + 64*tc (tc 0..15; bh%8 -> XCD, per-head K/V L2-resident).
// Wave w owns 16 t-cols (nt=1) -> 4096 waves = 4/SIMD (2x R9's residency).
// Loop (16 iters of 64 s): 8 V + 8 K coalesced 1KB b128 loads, 8 QK MFMA,
// 16 exp2 (no max: shift-invariant, |s|<~10 << 125), 8 PV MFMA.
__global__ __launch_bounds__(256) void attn10_kernel(const short* __restrict__ qbuf,
    const short* __restrict__ kbuf, const short* __restrict__ vbuf,
    short* __restrict__ attT){
  const int bid = blockIdx.x;
  const int bh = bid & 63, tc = bid >> 6;
  const int b = bh >> 3, h = bh & 7;
  const int tid = threadIdx.x;
  const int lane = tid & 63, w = tid >> 6;
  const int lm = lane & 15, lb = lane >> 4;
  const int tw = tc*64 + w*16;       // wave's 16 t-columns

  const short* qb = qbuf + (size_t)b*524288 + h*64;
  const short* kb = kbuf + (size_t)b*524288 + (size_t)h*65536 + lane*8;
  const short* vb = vbuf + (size_t)b*524288 + (size_t)h*65536 + lane*8;

  __shared__ short Tl[64*72];        // epilogue transpose only

  // Q frags (read-once), contiguous k-map
  s16x8 qf[2];
  #pragma unroll
  for (int ks = 0; ks < 2; ++ks)
    qf[ks] = *(const s16x8*)(qb + (size_t)(tw + lm)*512 + ks*32 + 8*lb);

  f32x4 of[4] = {};
  float lsum = 0.f;                  // per-lane partial, reduced once at end
  s16x8 pbf[2];

  for (int it = 0; it < 16; ++it){
    // V frags first (consumed last -> latency hidden under QK + exp)
    s16x8 vf[2][4];
    #pragma unroll
    for (int ks2 = 0; ks2 < 2; ++ks2)
      #pragma unroll
      for (int cs = 0; cs < 4; ++cs)
        vf[ks2][cs] = *(const s16x8*)(vb + (size_t)(cs*32 + it*2 + ks2)*512);

    // QK^T: S'[s][t]
    f32x4 sf[4];
    #pragma unroll
    for (int ms = 0; ms < 4; ++ms) sf[ms] = 0.f;
    #pragma unroll
    for (int ks = 0; ks < 2; ++ks){
      s16x8 kf[4];
      #pragma unroll
      for (int ms = 0; ms < 4; ++ms)
        kf[ms] = *(const s16x8*)(kb + (size_t)((it*4 + ms)*2 + ks)*512);
      #pragma unroll
      for (int ms = 0; ms < 4; ++ms)
        sf[ms] = mfma_bf16_16x16x32(kf[ms], qf[ks], sf[ms]);
    }

    // p = exp2(s) directly
    #pragma unroll
    for (int ms = 0; ms < 4; ++ms)
      #pragma unroll
      for (int r = 0; r < 4; ++r){
        const float e = __builtin_amdgcn_exp2f(sf[ms][r]);
        lsum += e;
        pbf[ms >> 1][(ms & 1)*4 + r] = f2bf(e);
      }

    // PV: D[c][t] = mfma(A=V frag, B=P' in-lane)
    #pragma unroll
    for (int ks2 = 0; ks2 < 2; ++ks2)
      #pragma unroll
      for (int cs = 0; cs < 4; ++cs)
        of[cs] = mfma_bf16_16x16x32(vf[ks2][cs], pbf[ks2], of[cs]);
  }

  // reduce l partials across the 4 lb groups (s was spread over lb only)
  lsum += __shfl_xor(lsum, 16, 64);
  lsum += __shfl_xor(lsum, 32, 64);
  const float inv = 1.f / lsum;

  // transpose [c][t] regs -> attT[b][t][c] via LDS
  #pragma unroll
  for (int cs = 0; cs < 4; ++cs){
    s16x4 o;
    #pragma unroll
    for (int r = 0; r < 4; ++r) o[r] = f2bf(of[cs][r] * inv);
    *(s16x4*)&Tl[(w*16 + lm)*72 + cs*16 + 4*lb] = o;
  }
  __syncthreads();
  short* outb = attT + (size_t)b*524288 + (size_t)(tc*64)*512 + h*64;
  #pragma unroll
  for (int i = 0; i < 2; ++i){
    const int g = tid + i*256, r = g >> 3, c8 = g & 7;
    *(uint4*)(outb + (size_t)r*512 + c8*8) = *(const uint4*)&Tl[r*72 + c8*8];
  }
}

// ---------------------------------------------------------------------------
extern "C" void kernel_launch(void* const* d_in, const int* in_sizes, int n_in,
                              void* d_out, int out_size, void* d_ws, size_t ws_size,
                              hipStream_t stream){
  const float* x      = (const float*)d_in[0];
  const float* norm_w = (const float*)d_in[1];
  const float* norm_b = (const float*)d_in[2];
  const float* qkv_w  = (const float*)d_in[3];
  const float* qkv_b  = (const float*)d_in[4];
  const float* proj_w = (const float*)d_in[5];
  const float* proj_b = (const float*)d_in[6];

  char* ws = (char*)d_ws;
  float2* stats = (float2*)(ws);                    // 4 KB
  short*  xnT   = (short*)(ws + 4096);              // 8 MiB
  short*  qwb   = (short*)(ws + 8392704);           // 1.5 MiB
  short*  pwb   = (short*)(ws + 9965568);           // 0.5 MiB
  short*  qbuf  = (short*)(ws + 10489856);          // 8 MiB
  short*  kbuf  = (short*)(ws + 18878464);          // 8 MiB (frag tiles)
  short*  vbuf  = (short*)(ws + 27267072);          // 8 MiB (frag tiles)
  short*  attT  = (short*)(ws + 35655680);          // 8 MiB

  prep_kernel<<<dim3(768), dim3(256), 0, stream>>>(x, stats, qkv_w, proj_w, qwb, pwb);
  gn_norm_t_kernel<<<dim3(16, 8), dim3(256), 0, stream>>>(x, norm_w, norm_b, stats, xnT);
  gemm_k512<0,128><<<dim3(8, 8, 12), dim3(256), 0, stream>>>(qwb, xnT, qkv_b, nullptr,
      (void*)qbuf, (void*)kbuf, (void*)vbuf);
  attn10_kernel<<<dim3(1024), dim3(256), 0, stream>>>(qbuf, kbuf, vbuf, attT);
  gemm_k512<2,64><<<dim3(8, 4, 16), dim3(256), 0, stream>>>(pwb, attT, proj_b, x,
      d_out, nullptr, nullptr);
}

// Round 13
// 84.087 us; speedup vs baseline: 1.1094x; 1.1094x over previous
//
#include <hip/hip_runtime.h>
#include <stdint.h>

// ---------------------------------------------------------------------------
// AttentionBlock: GroupNorm(32) -> qkv 1x1 -> 8-head attention (T=1024,ch=64)
//                 -> proj 1x1 + residual.  B=8, C=512, T=1024. fp32 I/O,
//                 bf16 MFMA internally.  5 kernels:
//   prep   : gn group stats (256 blk) + weight fp32->bf16 cvt (512 blk)
//   gn_norm: normalize+affine -> bf16 xnT[b][t][c] (t-major, LDS transpose)
//   gemmQKV: fused, 3 block types: Q = D[t][o] -> qbuf[b][t][512];
//            K = D[ck][t] (V-orientation) -> kbuf frag-tiles, s16x4 stores;
//            V = D[t][o'] -> vbuf frag-tiles, s16x4 stores.
//   attn   : barrier-free flash, 256 blk x 8 waves x 32t (ONE block/CU; all
//            8 waves share one K/V stream -> L1 dedup, L2 fetch halved);
//            K-frag ping-pong prefetch hides L2 latency; exp2 direct
//            (no max: |s|<~10, softmax shift-invariant); l per-lane.
//   proj   : D[o][t] = Wp x att + bias + x -> d_out; LDS-transposed epilogue.
// Frag-tile layout (1KB): addr = tile*512 + lane*8 + j; A/B share slot->k map
//   so the HW k-permutation cancels.
// Lessons: R4 spills; R5 LDS>64K; R7 split-s traffic; R8 strided V reads;
//   R9/R10 scattered 2B stores; R12 t-split halved arith intensity and
//   doubled L2 fetch -> regression. attn is L2-stream-bound: dedup, don't
//   add consumers.
// ---------------------------------------------------------------------------

typedef float  f32x4  __attribute__((ext_vector_type(4)));
typedef short  s16x4  __attribute__((ext_vector_type(4)));
typedef short  s16x8  __attribute__((ext_vector_type(8)));
typedef __bf16 bf16x8 __attribute__((ext_vector_type(8)));

#define QK_SCALE 0.4246609f   // sqrt(0.125 * log2(e))

__device__ __forceinline__ f32x4 mfma_bf16_16x16x32(s16x8 a, s16x8 b, f32x4 c){
  return __builtin_amdgcn_mfma_f32_16x16x32_bf16(
      __builtin_bit_cast(bf16x8, a), __builtin_bit_cast(bf16x8, b), c, 0, 0, 0);
}

__device__ __forceinline__ short f2bf(float v){
  return __builtin_bit_cast(short, static_cast<__bf16>(v));
}

// async global->LDS, 16B per lane; dest = firstlane-base + lane*16 (linear)
__device__ __forceinline__ void gload16(const void* g, void* l){
  __builtin_amdgcn_global_load_lds(
      (const __attribute__((address_space(1))) void*)g,
      (__attribute__((address_space(3))) void*)l, 16, 0, 0);
}

// ---------------------------------------------------------------------------
// prep: blocks 0..255 = GroupNorm stats per (b,g); blocks 256..767 = weight cvt
__global__ __launch_bounds__(256) void prep_kernel(const float* __restrict__ x,
    float2* __restrict__ stats, const float* __restrict__ qkv_w,
    const float* __restrict__ proj_w, short* __restrict__ qwb,
    short* __restrict__ pwb){
  if (blockIdx.x < 256){
    __shared__ float ss[256], sq[256];
    const int bg = blockIdx.x;
    const float4* base = (const float4*)(x + (size_t)bg * 16384);
    float s = 0.f, q = 0.f;
    #pragma unroll
    for (int i = 0; i < 16; ++i){
      float4 v = base[threadIdx.x + i*256];
      s += v.x + v.y + v.z + v.w;
      q += v.x*v.x + v.y*v.y + v.z*v.z + v.w*v.w;
    }
    ss[threadIdx.x] = s; sq[threadIdx.x] = q;
    __syncthreads();
    for (int off = 128; off > 0; off >>= 1){
      if (threadIdx.x < off){ ss[threadIdx.x] += ss[threadIdx.x+off];
                              sq[threadIdx.x] += sq[threadIdx.x+off]; }
      __syncthreads();
    }
    if (threadIdx.x == 0){
      float mu  = ss[0] * (1.f/16384.f);
      float var = sq[0] * (1.f/16384.f) - mu*mu;   // biased (matches jnp.var)
      stats[bg] = make_float2(mu, rsqrtf(var + 1e-5f));
    }
  } else {
    const int i = (blockIdx.x - 256)*256 + threadIdx.x;   // 0..131071
    const float* in; short* out; float s;
    if (i < 98304){
      in = qkv_w + (size_t)i*8; out = qwb + (size_t)i*8;
      s = (((i >> 6) % 192) < 128) ? QK_SCALE : 1.f;     // q,k rows pre-scaled
    } else {
      const int j = i - 98304;
      in = proj_w + (size_t)j*8; out = pwb + (size_t)j*8;
      s = 1.f;
    }
    const float4* p = (const float4*)in;
    float4 a = p[0], b = p[1];
    s16x8 o;
    o[0]=f2bf(a.x*s); o[1]=f2bf(a.y*s); o[2]=f2bf(a.z*s); o[3]=f2bf(a.w*s);
    o[4]=f2bf(b.x*s); o[5]=f2bf(b.y*s); o[6]=f2bf(b.z*s); o[7]=f2bf(b.w*s);
    *(s16x8*)out = o;
  }
}

// normalize + affine -> bf16 xnT[b][t][c] (transposed via LDS tile)
__global__ __launch_bounds__(256) void gn_norm_t_kernel(const float* __restrict__ x,
    const float* __restrict__ w, const float* __restrict__ bia,
    const float2* __restrict__ stats, short* __restrict__ xnT){
  const int t0 = blockIdx.x * 64, b = blockIdx.y;
  const int tid = threadIdx.x;
  __shared__ short L[64*68];                 // [c][t] pad->68
  const float* xb = x   + (size_t)b * 524288;
  short*       ob = xnT + (size_t)b * 524288;
  for (int cc = 0; cc < 8; ++cc){
    #pragma unroll
    for (int i = 0; i < 4; ++i){
      const int f  = tid + i*256;            // 0..1023
      const int cl = f >> 4, t4 = (f & 15) * 4;
      const int ch = cc*64 + cl;
      const float2 st = stats[b*32 + (ch >> 4)];
      const float sc = st.y * w[ch];
      const float sh = bia[ch] - st.x * sc;
      float4 v = *(const float4*)(xb + (size_t)ch*1024 + t0 + t4);
      s16x4 o;
      o[0]=f2bf(v.x*sc+sh); o[1]=f2bf(v.y*sc+sh); o[2]=f2bf(v.z*sc+sh); o[3]=f2bf(v.w*sc+sh);
      *(s16x4*)&L[cl*68 + t4] = o;
    }
    __syncthreads();
    #pragma unroll
    for (int i = 0; i < 2; ++i){
      const int g  = tid + i*256;            // 0..511
      const int tl = g >> 3, c8 = g & 7;
      s16x8 o;
      #pragma unroll
      for (int j = 0; j < 8; ++j) o[j] = L[(c8*8 + j)*68 + tl];
      *(s16x8*)(ob + (size_t)(t0 + tl)*512 + cc*64 + c8*8) = o;
    }
    __syncthreads();
  }
}

// ---------------------------------------------------------------------------
// Unified K=512 GEMM, 128xNB tile, BK=32, 4 waves (2x2).
// Staging: global_load_lds w=16 into linear [row][32] tiles; XOR swizzle
// slot = lb ^ ((row>>1)&3) on reads, source chunk (c&3)^((c>>3)&3) on stage.
// MODE 0 (NB=128, fused QKV), block type by z:
//   z<4 : Q: A=xnT t-rows (m0=y*128), B=Wq o-rows (n0=z*128)   -> qbuf[t][512]
//   4-7 : K: A=Wk ck-rows (m0=(z-4)*128), B=xnT t-rows (n0=y*128)
//         -> kbuf frag-tiles, r-contiguous s16x4 (512B/instr segments)
//   8-11: V: A=xnT t-rows (m0=y*128), B=Wv o'-rows (n0=1024+(z-8)*128)
//         -> vbuf frag-tiles, s16x4 stores
// MODE 2 (NB=64): A=Wp o-rows, B=attT t-rows -> f32 out via LDS-transposed
//   epilogue: 256B-coalesced float4 resid-add/store.
template<int MODE, int NB>
__global__ __launch_bounds__(256) void gemm_k512(const short* __restrict__ W,
    const short* __restrict__ act, const float* __restrict__ bias,
    const float* __restrict__ resid, void* __restrict__ outp,
    void* __restrict__ outp2, void* __restrict__ outp3){
  constexpr int NSF = NB / 32;      // n-frags per wave
  constexpr int SMEM_BYTES = (MODE == 2) ? 34816 : 32768;
  const int b  = blockIdx.x;
  const int tid  = threadIdx.x;
  const int lane = tid & 63, w = tid >> 6;
  const int wm = w >> 1, wn = w & 1;
  const int lm = lane & 15, lb = lane >> 4;
  const int xr = (lm >> 1) & 3;     // row-swizzle term for frag reads

  int part, m0, n0;
  if constexpr (MODE == 0){
    const int z = blockIdx.z;
    part = (z >= 8) ? 2 : (z >= 4 ? 1 : 0);
    m0 = (part == 1) ? (z - 4)*128 : blockIdx.y*128;
    n0 = (part == 0) ? z*128 : (part == 1 ? blockIdx.y*128 : 1024 + (z - 8)*128);
  } else {
    part = 0; m0 = blockIdx.y*128; n0 = blockIdx.z*NB;
  }

  __shared__ __align__(16) char smem[SMEM_BYTES];
  short* Asb = (short*)smem;                 // [2][128*32]
  short* Bsb = (short*)(smem + 16384);       // [2][NB*32]

  const short* actb = act + (size_t)b * 524288;

  auto arow = [&](int r) -> const short* {
    if constexpr (MODE == 0){
      if (part == 1){
        const int m = m0 + r;
        return W + (size_t)(192*(m>>6) + 64 + (m&63)) * 512;
      }
      return actb + (size_t)(m0 + r) * 512;
    } else {
      return W + (size_t)(m0 + r) * 512;
    }
  };
  auto brow = [&](int r) -> const short* {
    if constexpr (MODE == 0){
      if (part == 1) return actb + (size_t)(n0 + r) * 512;
      const int o = n0 + r;
      return W + (size_t)(192*((o>>6)&7) + (o>>9)*64 + (o&63)) * 512;
    } else {
      return actb + (size_t)(n0 + r) * 512;
    }
  };

  // stage K-tile t into buf: async gload_lds; source chunk pre-swizzled
  auto stage = [&](int t, int buf){
    const int k0 = t * 32;
    #pragma unroll
    for (int i = 0; i < 2; ++i){
      const int c = tid + i*256;
      const int r = c >> 2, sj = (c & 3) ^ ((c >> 3) & 3);
      gload16(arow(r) + k0 + sj*8, Asb + buf*4096 + (c>>2)*32 + (c&3)*8);
    }
    #pragma unroll
    for (int i = 0; i < NB/64; ++i){
      const int c = tid + i*256;
      const int r = c >> 2, sj = (c & 3) ^ ((c >> 3) & 3);
      gload16(brow(r) + k0 + sj*8, Bsb + buf*(NB*32) + (c>>2)*32 + (c&3)*8);
    }
  };

  f32x4 acc[4][NSF] = {};
  stage(0, 0);

  for (int t = 0; t < 16; ++t){
    __syncthreads();                 // waits vmcnt(0) for prior stage
    if (t + 1 < 16) stage(t + 1, (t + 1) & 1);
    const int buf = t & 1;

    s16x8 af[4], bfr[NSF];
    #pragma unroll
    for (int ms = 0; ms < 4; ++ms){
      const int row = wm*64 + ms*16 + lm;
      af[ms] = *(const s16x8*)(Asb + buf*4096 + row*32 + ((lb ^ xr) << 3));
    }
    #pragma unroll
    for (int ns = 0; ns < NSF; ++ns){
      const int row = wn*(NB/2) + ns*16 + lm;
      bfr[ns] = *(const s16x8*)(Bsb + buf*(NB*32) + row*32 + ((lb ^ xr) << 3));
    }
    #pragma unroll
    for (int ns = 0; ns < NSF; ++ns)
      #pragma unroll
      for (int ms = 0; ms < 4; ++ms)
        acc[ms][ns] = mfma_bf16_16x16x32(af[ms], bfr[ns], acc[ms][ns]);
  }

  // C/D: col = lane&15, row = 4*(lane>>4) + reg   (m89)
  const int mo = m0 + wm*64, no = n0 + wn*(NB/2);
  if constexpr (MODE == 0){
    if (part == 0){
      short* qout = (short*)outp + (size_t)b * 524288;     // [t][512]
      float bn[NSF];
      #pragma unroll
      for (int ns = 0; ns < NSF; ++ns){
        const int o = no + ns*16 + lm;
        bn[ns] = QK_SCALE * bias[192*((o>>6)&7) + (o&63)];
      }
      #pragma unroll
      for (int ms = 0; ms < 4; ++ms)
        #pragma unroll
        for (int ns = 0; ns < NSF; ++ns)
          #pragma unroll
          for (int r = 0; r < 4; ++r){
            const int m = mo + ms*16 + 4*lb + r;
            const int n = no + ns*16 + lm;
            qout[(size_t)m*512 + n] = f2bf(acc[ms][ns][r] + bn[ns]);
          }
    } else if (part == 1){
      // K in D[ck][t] orientation: m = channel, n = s; r-contiguous tiles.
      short* kout = (short*)outp2 + (size_t)b * 524288;    // frag tiles
      const int hh = m0/64 + wm;                           // m>>6, wave-uniform
      float bm[16];
      #pragma unroll
      for (int ms = 0; ms < 4; ++ms)
        #pragma unroll
        for (int r = 0; r < 4; ++r){
          const int m = mo + ms*16 + 4*lb + r;
          bm[ms*4+r] = QK_SCALE * bias[192*(m>>6) + 64 + (m&63)];
        }
      #pragma unroll
      for (int ms = 0; ms < 4; ++ms)
        #pragma unroll
        for (int ns = 0; ns < NSF; ++ns){
          const int n = no + ns*16 + lm;                   // s
          const size_t a = ((size_t)hh*128 + (n>>4)*2 + (ms>>1))*512
                         + (((ms*2 + (lb>>1)) & 3)*16 + (n&15))*8 + 4*(lb&1);
          s16x4 o;
          #pragma unroll
          for (int r = 0; r < 4; ++r) o[r] = f2bf(acc[ms][ns][r] + bm[ms*4+r]);
          *(s16x4*)(kout + a) = o;
        }
    } else {
      short* vout = (short*)outp3 + (size_t)b * 524288;    // frag tiles
      float bn[NSF];
      #pragma unroll
      for (int ns = 0; ns < NSF; ++ns){
        const int o = no + ns*16 + lm;
        bn[ns] = bias[192*((o>>6)&7) + (o>>9)*64 + (o&63)];
      }
      #pragma unroll
      for (int ms = 0; ms < 4; ++ms)
        #pragma unroll
        for (int ns = 0; ns < NSF; ++ns){
          const int m = mo + ms*16 + 4*lb;                 // r=0 row; s = m+r
          const int n = no + ns*16 + lm;
          const int h = (n >> 6) & 7, c = n & 63;
          const size_t a = ((size_t)h*128 + (c>>4)*32 + (m>>5))*512
                         + (((m>>2)&3)*16 + (c&15))*8 + ((m>>4)&1)*4;
          s16x4 o;
          #pragma unroll
          for (int r = 0; r < 4; ++r) o[r] = f2bf(acc[ms][ns][r] + bn[ns]);
          *(s16x4*)(vout + a) = o;
        }
    }
  } else {
    // proj: LDS-transposed epilogue -> coalesced float4 resid-add/store
    __syncthreads();                          // staging reads done
    float* Lf = (float*)smem;                 // [128][68] f32
    #pragma unroll
    for (int ms = 0; ms < 4; ++ms)
      #pragma unroll
      for (int ns = 0; ns < NSF; ++ns)
        #pragma unroll
        for (int r = 0; r < 4; ++r)
          Lf[(wm*64 + ms*16 + 4*lb + r)*68 + wn*32 + ns*16 + lm] = acc[ms][ns][r];
    __syncthreads();
    float* out = (float*)outp + (size_t)b * 524288;
    const float* xr2 = resid + (size_t)b * 524288;
    #pragma unroll
    for (int p = 0; p < 8; ++p){
      const int row = p*16 + (tid >> 4);
      const int c4  = (tid & 15) * 4;
      float4 v = *(const float4*)&Lf[row*68 + c4];
      const float bs = bias[m0 + row];
      const size_t off = (size_t)(m0 + row)*1024 + n0 + c4;
      float4 rv = *(const float4*)(xr2 + off);
      float4 ov = make_float4(v.x+bs+rv.x, v.y+bs+rv.y, v.z+bs+rv.z, v.w+bs+rv.w);
      *(float4*)(out + off) = ov;
    }
  }
}

// ---------------------------------------------------------------------------
// Attention v11: barrier-free, ONE block per CU. 256 blocks x 512 thr;
// bid = bh + 64*tc (tc 0..3; bh%8 -> XCD). Wave w (0..7) owns 32 t-cols of a
// 256-t chunk. All 8 waves read IDENTICAL K/V addresses -> one L2 stream per
// CU (L1 dedup), halving L2 fetch vs 2-blocks/CU. K-frag ping-pong prefetch
// (kA/kB, static indices) hides L2 latency under exp2+PV. exp2 direct
// (no max: shift-invariant, |s|<~10 << 125). l per-lane, reduced once.
__global__ __launch_bounds__(512) void attn11_kernel(const short* __restrict__ qbuf,
    const short* __restrict__ kbuf, const short* __restrict__ vbuf,
    short* __restrict__ attT){
  const int bid = blockIdx.x;
  const int bh = bid & 63, tc = bid >> 6;
  const int b = bh >> 3, h = bh & 7;
  const int tid = threadIdx.x;
  const int lane = tid & 63, w = tid >> 6;
  const int lm = lane & 15, lb = lane >> 4;
  const int t0 = tc * 256;

  const short* qb = qbuf + (size_t)b*524288 + h*64;
  const short* kb = kbuf + (size_t)b*524288 + (size_t)h*65536 + lane*8;
  const short* vb = vbuf + (size_t)b*524288 + (size_t)h*65536 + lane*8;

  __shared__ short Tl[256*72];       // epilogue transpose only (36864 B)

  // Q frags (read-once), contiguous k-map
  s16x8 qf[2][2];
  #pragma unroll
  for (int tb = 0; tb < 2; ++tb)
    #pragma unroll
    for (int ks = 0; ks < 2; ++ks)
      qf[tb][ks] = *(const s16x8*)(qb + (size_t)(t0 + w*32 + tb*16 + lm)*512
                                      + ks*32 + 8*lb);

  f32x4 of[2][4] = {};
  float lsum[2] = {0.f, 0.f};        // per-lane partials, reduced once at end
  s16x8 kA[2][4], kB[2][4];

  auto load_k = [&](int it, s16x8 (&kf)[2][4]){
    #pragma unroll
    for (int ks = 0; ks < 2; ++ks)
      #pragma unroll
      for (int ms = 0; ms < 4; ++ms)
        kf[ks][ms] = *(const s16x8*)(kb + (size_t)((it*4 + ms)*2 + ks)*512);
  };

  auto body = [&](int it, s16x8 (&kcur)[2][4], s16x8 (&knxt)[2][4]){
    // V frags for this iter (consumed last -> latency hidden under QK+exp)
    s16x8 vf[2][4];
    #pragma unroll
    for (int ks2 = 0; ks2 < 2; ++ks2)
      #pragma unroll
      for (int cs = 0; cs < 4; ++cs)
        vf[ks2][cs] = *(const s16x8*)(vb + (size_t)(cs*32 + it*2 + ks2)*512);

    // prefetch next iter's K frags (consumed next body -> latency hidden)
    if (it + 1 < 16) load_k(it + 1, knxt);

    // QK^T: S'[s][t]
    f32x4 sf[2][4];
    #pragma unroll
    for (int tb = 0; tb < 2; ++tb)
      #pragma unroll
      for (int ms = 0; ms < 4; ++ms) sf[tb][ms] = 0.f;
    #pragma unroll
    for (int ks = 0; ks < 2; ++ks)
      #pragma unroll
      for (int ms = 0; ms < 4; ++ms){
        sf[0][ms] = mfma_bf16_16x16x32(kcur[ks][ms], qf[0][ks], sf[0][ms]);
        sf[1][ms] = mfma_bf16_16x16x32(kcur[ks][ms], qf[1][ks], sf[1][ms]);
      }

    // p = exp2(s) directly
    s16x8 pbf[2][2];
    #pragma unroll
    for (int tb = 0; tb < 2; ++tb)
      #pragma unroll
      for (int ms = 0; ms < 4; ++ms)
        #pragma unroll
        for (int r = 0; r < 4; ++r){
          const float e = __builtin_amdgcn_exp2f(sf[tb][ms][r]);
          lsum[tb] += e;
          pbf[tb][ms >> 1][(ms & 1)*4 + r] = f2bf(e);
        }

    // PV: D[c][t] = mfma(A=V frag, B=P' in-lane)
    #pragma unroll
    for (int ks2 = 0; ks2 < 2; ++ks2)
      #pragma unroll
      for (int cs = 0; cs < 4; ++cs){
        of[0][cs] = mfma_bf16_16x16x32(vf[ks2][cs], pbf[0][ks2], of[0][cs]);
        of[1][cs] = mfma_bf16_16x16x32(vf[ks2][cs], pbf[1][ks2], of[1][cs]);
      }
  };

  load_k(0, kA);
  for (int it2 = 0; it2 < 16; it2 += 2){
    body(it2,     kA, kB);
    body(it2 + 1, kB, kA);
  }

  // reduce l partials across the 4 lb groups (s was spread over lb only)
  #pragma unroll
  for (int tb = 0; tb < 2; ++tb){
    lsum[tb] += __shfl_xor(lsum[tb], 16, 64);
    lsum[tb] += __shfl_xor(lsum[tb], 32, 64);
  }
  const float inv0 = 1.f / lsum[0], inv1 = 1.f / lsum[1];

  // transpose [c][t] regs -> attT[b][t][c] via LDS
  #pragma unroll
  for (int tb = 0; tb < 2; ++tb)
    #pragma unroll
    for (int cs = 0; cs < 4; ++cs){
      s16x4 o;
      #pragma unroll
      for (int r = 0; r < 4; ++r)
        o[r] = f2bf(of[tb][cs][r] * (tb ? inv1 : inv0));
      *(s16x4*)&Tl[(w*32 + tb*16 + lm)*72 + cs*16 + 4*lb] = o;
    }
  __syncthreads();
  short* outb = attT + (size_t)b*524288 + (size_t)t0*512 + h*64;
  #pragma unroll
  for (int i = 0; i < 4; ++i){
    const int g = tid + i*512, r = g >> 3, c8 = g & 7;
    *(uint4*)(outb + (size_t)r*512 + c8*8) = *(const uint4*)&Tl[r*72 + c8*8];
  }
}

// ---------------------------------------------------------------------------
extern "C" void kernel_launch(void* const* d_in, const int* in_sizes, int n_in,
                              void* d_out, int out_size, void* d_ws, size_t ws_size,
                              hipStream_t stream){
  const float* x      = (const float*)d_in[0];
  const float* norm_w = (const float*)d_in[1];
  const float* norm_b = (const float*)d_in[2];
  const float* qkv_w  = (const float*)d_in[3];
  const float* qkv_b  = (const float*)d_in[4];
  const float* proj_w = (const float*)d_in[5];
  const float* proj_b = (const float*)d_in[6];

  char* ws = (char*)d_ws;
  float2* stats = (float2*)(ws);                    // 4 KB
  short*  xnT   = (short*)(ws + 4096);              // 8 MiB
  short*  qwb   = (short*)(ws + 8392704);           // 1.5 MiB
  short*  pwb   = (short*)(ws + 9965568);           // 0.5 MiB
  short*  qbuf  = (short*)(ws + 10489856);          // 8 MiB
  short*  kbuf  = (short*)(ws + 18878464);          // 8 MiB (frag tiles)
  short*  vbuf  = (short*)(ws + 27267072);          // 8 MiB (frag tiles)
  short*  attT  = (short*)(ws + 35655680);          // 8 MiB

  prep_kernel<<<dim3(768), dim3(256), 0, stream>>>(x, stats, qkv_w, proj_w, qwb, pwb);
  gn_norm_t_kernel<<<dim3(16, 8), dim3(256), 0, stream>>>(x, norm_w, norm_b, stats, xnT);
  gemm_k512<0,128><<<dim3(8, 8, 12), dim3(256), 0, stream>>>(qwb, xnT, qkv_b, nullptr,
      (void*)qbuf, (void*)kbuf, (void*)vbuf);
  attn11_kernel<<<dim3(256), dim3(512), 0, stream>>>(qbuf, kbuf, vbuf, attT);
  gemm_k512<2,64><<<dim3(8, 4, 16), dim3(256), 0, stream>>>(pwb, attT, proj_b, x,
      d_out, nullptr, nullptr);
}

// Round 14
// 82.140 us; speedup vs baseline: 1.1356x; 1.0237x over previous
//
#include <hip/hip_runtime.h>
#include <stdint.h>

// ---------------------------------------------------------------------------
// AttentionBlock: GroupNorm(32) -> qkv 1x1 -> 8-head attention (T=1024,ch=64)
//                 -> proj 1x1 + residual.  B=8, C=512, T=1024. fp32 I/O,
//                 bf16 MFMA internally.  5 kernels:
//   prep   : gn group stats (256 blk) + weight fp32->bf16 cvt (512 blk)
//   gn_norm: normalize+affine -> bf16 xnT[b][t][c] (t-major, LDS transpose)
//   gemmQKV: fused; Q,K = D[c][t] = W x xnT -> frag-tiles (r-contiguous
//            s16x4 stores); V = D[t][o'] -> frag-tiles (s16x4 stores).
//   attn   : barrier-free flash (R11/R13 structure): 256 blk x 8 waves x 32t,
//            1 blk/CU, shared K/V stream, K ping-pong prefetch; Q/K/V frags
//            ALL coalesced 1KB b128 loads; exp2 direct (no max: |s|<~10,
//            softmax shift-invariant); lsum as f32x4 (4 indep add chains).
//   proj   : D[o][t] = Wp x att + bias + x -> d_out; LDS-transposed epilogue.
// Frag-tile layout (1KB): addr = tile*512 + lane*8 + j; A/B share slot->k map
//   so the HW k-permutation cancels. Q uses the K formula (s<->t roles).
// Lessons: R4 spills; R5 LDS>64K; R7/R12 split adds traffic (attn is small &
//   hidden); R8 strided reads; R9-R11 scattered 2B stores (Q fixed HERE —
//   the last uncoalesced surface); R13 attn scheduling = null.
// ---------------------------------------------------------------------------

typedef float  f32x4  __attribute__((ext_vector_type(4)));
typedef short  s16x4  __attribute__((ext_vector_type(4)));
typedef short  s16x8  __attribute__((ext_vector_type(8)));
typedef __bf16 bf16x8 __attribute__((ext_vector_type(8)));

#define QK_SCALE 0.4246609f   // sqrt(0.125 * log2(e))

__device__ __forceinline__ f32x4 mfma_bf16_16x16x32(s16x8 a, s16x8 b, f32x4 c){
  return __builtin_amdgcn_mfma_f32_16x16x32_bf16(
      __builtin_bit_cast(bf16x8, a), __builtin_bit_cast(bf16x8, b), c, 0, 0, 0);
}

__device__ __forceinline__ short f2bf(float v){
  return __builtin_bit_cast(short, static_cast<__bf16>(v));
}

// async global->LDS, 16B per lane; dest = firstlane-base + lane*16 (linear)
__device__ __forceinline__ void gload16(const void* g, void* l){
  __builtin_amdgcn_global_load_lds(
      (const __attribute__((address_space(1))) void*)g,
      (__attribute__((address_space(3))) void*)l, 16, 0, 0);
}

// ---------------------------------------------------------------------------
// prep: blocks 0..255 = GroupNorm stats per (b,g); blocks 256..767 = weight cvt
__global__ __launch_bounds__(256) void prep_kernel(const float* __restrict__ x,
    float2* __restrict__ stats, const float* __restrict__ qkv_w,
    const float* __restrict__ proj_w, short* __restrict__ qwb,
    short* __restrict__ pwb){
  if (blockIdx.x < 256){
    __shared__ float ss[256], sq[256];
    const int bg = blockIdx.x;
    const float4* base = (const float4*)(x + (size_t)bg * 16384);
    float s = 0.f, q = 0.f;
    #pragma unroll
    for (int i = 0; i < 16; ++i){
      float4 v = base[threadIdx.x + i*256];
      s += v.x + v.y + v.z + v.w;
      q += v.x*v.x + v.y*v.y + v.z*v.z + v.w*v.w;
    }
    ss[threadIdx.x] = s; sq[threadIdx.x] = q;
    __syncthreads();
    for (int off = 128; off > 0; off >>= 1){
      if (threadIdx.x < off){ ss[threadIdx.x] += ss[threadIdx.x+off];
                              sq[threadIdx.x] += sq[threadIdx.x+off]; }
      __syncthreads();
    }
    if (threadIdx.x == 0){
      float mu  = ss[0] * (1.f/16384.f);
      float var = sq[0] * (1.f/16384.f) - mu*mu;   // biased (matches jnp.var)
      stats[bg] = make_float2(mu, rsqrtf(var + 1e-5f));
    }
  } else {
    const int i = (blockIdx.x - 256)*256 + threadIdx.x;   // 0..131071
    const float* in; short* out; float s;
    if (i < 98304){
      in = qkv_w + (size_t)i*8; out = qwb + (size_t)i*8;
      s = (((i >> 6) % 192) < 128) ? QK_SCALE : 1.f;     // q,k rows pre-scaled
    } else {
      const int j = i - 98304;
      in = proj_w + (size_t)j*8; out = pwb + (size_t)j*8;
      s = 1.f;
    }
    const float4* p = (const float4*)in;
    float4 a = p[0], b = p[1];
    s16x8 o;
    o[0]=f2bf(a.x*s); o[1]=f2bf(a.y*s); o[2]=f2bf(a.z*s); o[3]=f2bf(a.w*s);
    o[4]=f2bf(b.x*s); o[5]=f2bf(b.y*s); o[6]=f2bf(b.z*s); o[7]=f2bf(b.w*s);
    *(s16x8*)out = o;
  }
}

// normalize + affine -> bf16 xnT[b][t][c] (transposed via LDS tile)
__global__ __launch_bounds__(256) void gn_norm_t_kernel(const float* __restrict__ x,
    const float* __restrict__ w, const float* __restrict__ bia,
    const float2* __restrict__ stats, short* __restrict__ xnT){
  const int t0 = blockIdx.x * 64, b = blockIdx.y;
  const int tid = threadIdx.x;
  __shared__ short L[64*68];                 // [c][t] pad->68
  const float* xb = x   + (size_t)b * 524288;
  short*       ob = xnT + (size_t)b * 524288;
  for (int cc = 0; cc < 8; ++cc){
    #pragma unroll
    for (int i = 0; i < 4; ++i){
      const int f  = tid + i*256;            // 0..1023
      const int cl = f >> 4, t4 = (f & 15) * 4;
      const int ch = cc*64 + cl;
      const float2 st = stats[b*32 + (ch >> 4)];
      const float sc = st.y * w[ch];
      const float sh = bia[ch] - st.x * sc;
      float4 v = *(const float4*)(xb + (size_t)ch*1024 + t0 + t4);
      s16x4 o;
      o[0]=f2bf(v.x*sc+sh); o[1]=f2bf(v.y*sc+sh); o[2]=f2bf(v.z*sc+sh); o[3]=f2bf(v.w*sc+sh);
      *(s16x4*)&L[cl*68 + t4] = o;
    }
    __syncthreads();
    #pragma unroll
    for (int i = 0; i < 2; ++i){
      const int g  = tid + i*256;            // 0..511
      const int tl = g >> 3, c8 = g & 7;
      s16x8 o;
      #pragma unroll
      for (int j = 0; j < 8; ++j) o[j] = L[(c8*8 + j)*68 + tl];
      *(s16x8*)(ob + (size_t)(t0 + tl)*512 + cc*64 + c8*8) = o;
    }
    __syncthreads();
  }
}

// ---------------------------------------------------------------------------
// Unified K=512 GEMM, 128xNB tile, BK=32, 4 waves (2x2).
// Staging: global_load_lds w=16 into linear [row][32] tiles; XOR swizzle
// slot = lb ^ ((row>>1)&3) on reads, source chunk (c&3)^((c>>3)&3) on stage.
// MODE 0 (NB=128, fused QKV), part = z>>2:
//   part 0 (Q), part 1 (K): D[c][t] = W x xnT. m0=(z&3)*128 (channel),
//     n0=y*128 (t). A=W rows 192*h + part*64 + c6; B=xnT rows t.
//     -> q/k frag-tiles, r-contiguous s16x4 stores (512B/instr segments).
//   part 2 (V): D[t][o'] (A=xnT m0=y*128, B=Wv n0=1024+(z&3)*128)
//     -> vbuf frag-tiles, s16x4 stores.
// MODE 2 (NB=64): A=Wp o-rows, B=attT t-rows -> f32 out via LDS-transposed
//   epilogue: 256B-coalesced float4 resid-add/store.
template<int MODE, int NB>
__global__ __launch_bounds__(256) void gemm_k512(const short* __restrict__ W,
    const short* __restrict__ act, const float* __restrict__ bias,
    const float* __restrict__ resid, void* __restrict__ outp,
    void* __restrict__ outp2, void* __restrict__ outp3){
  constexpr int NSF = NB / 32;      // n-frags per wave
  constexpr int SMEM_BYTES = (MODE == 2) ? 34816 : 32768;
  const int b  = blockIdx.x;
  const int tid  = threadIdx.x;
  const int lane = tid & 63, w = tid >> 6;
  const int wm = w >> 1, wn = w & 1;
  const int lm = lane & 15, lb = lane >> 4;
  const int xr = (lm >> 1) & 3;     // row-swizzle term for frag reads

  int part, m0, n0;
  if constexpr (MODE == 0){
    const int z = blockIdx.z;
    part = z >> 2;                  // 0=Q 1=K 2=V
    if (part < 2){ m0 = (z & 3)*128; n0 = blockIdx.y*128; }
    else         { m0 = blockIdx.y*128; n0 = 1024 + (z & 3)*128; }
  } else {
    part = 0; m0 = blockIdx.y*128; n0 = blockIdx.z*NB;
  }

  __shared__ __align__(16) char smem[SMEM_BYTES];
  short* Asb = (short*)smem;                 // [2][128*32]
  short* Bsb = (short*)(smem + 16384);       // [2][NB*32]

  const short* actb = act + (size_t)b * 524288;

  auto arow = [&](int r) -> const short* {
    if constexpr (MODE == 0){
      if (part < 2){
        const int m = m0 + r;
        return W + (size_t)(192*(m>>6) + part*64 + (m&63)) * 512;
      }
      return actb + (size_t)(m0 + r) * 512;
    } else {
      return W + (size_t)(m0 + r) * 512;
    }
  };
  auto brow = [&](int r) -> const short* {
    if constexpr (MODE == 0){
      if (part < 2) return actb + (size_t)(n0 + r) * 512;
      const int o = n0 + r;                   // 1024..1535
      return W + (size_t)(192*((o>>6)&7) + 128 + (o&63)) * 512;
    } else {
      return actb + (size_t)(n0 + r) * 512;
    }
  };

  // stage K-tile t into buf: async gload_lds; source chunk pre-swizzled
  auto stage = [&](int t, int buf){
    const int k0 = t * 32;
    #pragma unroll
    for (int i = 0; i < 2; ++i){
      const int c = tid + i*256;
      const int r = c >> 2, sj = (c & 3) ^ ((c >> 3) & 3);
      gload16(arow(r) + k0 + sj*8, Asb + buf*4096 + (c>>2)*32 + (c&3)*8);
    }
    #pragma unroll
    for (int i = 0; i < NB/64; ++i){
      const int c = tid + i*256;
      const int r = c >> 2, sj = (c & 3) ^ ((c >> 3) & 3);
      gload16(brow(r) + k0 + sj*8, Bsb + buf*(NB*32) + (c>>2)*32 + (c&3)*8);
    }
  };

  f32x4 acc[4][NSF] = {};
  stage(0, 0);

  for (int t = 0; t < 16; ++t){
    __syncthreads();                 // waits vmcnt(0) for prior stage
    if (t + 1 < 16) stage(t + 1, (t + 1) & 1);
    const int buf = t & 1;

    s16x8 af[4], bfr[NSF];
    #pragma unroll
    for (int ms = 0; ms < 4; ++ms){
      const int row = wm*64 + ms*16 + lm;
      af[ms] = *(const s16x8*)(Asb + buf*4096 + row*32 + ((lb ^ xr) << 3));
    }
    #pragma unroll
    for (int ns = 0; ns < NSF; ++ns){
      const int row = wn*(NB/2) + ns*16 + lm;
      bfr[ns] = *(const s16x8*)(Bsb + buf*(NB*32) + row*32 + ((lb ^ xr) << 3));
    }
    #pragma unroll
    for (int ns = 0; ns < NSF; ++ns)
      #pragma unroll
      for (int ms = 0; ms < 4; ++ms)
        acc[ms][ns] = mfma_bf16_16x16x32(af[ms], bfr[ns], acc[ms][ns]);
  }

  // C/D: col = lane&15, row = 4*(lane>>4) + reg   (m89)
  const int mo = m0 + wm*64, no = n0 + wn*(NB/2);
  if constexpr (MODE == 0){
    if (part < 2){
      // Q/K in D[c][t] orientation: m = channel, n = t/s; r-contiguous tiles.
      short* outT = (short*)(part == 0 ? outp : outp2) + (size_t)b * 524288;
      const int hh = m0/64 + wm;                           // m>>6, wave-uniform
      float bm[16];
      #pragma unroll
      for (int ms = 0; ms < 4; ++ms)
        #pragma unroll
        for (int r = 0; r < 4; ++r){
          const int m = mo + ms*16 + 4*lb + r;
          bm[ms*4+r] = QK_SCALE * bias[192*(m>>6) + part*64 + (m&63)];
        }
      #pragma unroll
      for (int ms = 0; ms < 4; ++ms)
        #pragma unroll
        for (int ns = 0; ns < NSF; ++ns){
          const int n = no + ns*16 + lm;                   // t (attn s/t)
          const size_t a = ((size_t)hh*128 + (n>>4)*2 + (ms>>1))*512
                         + (((ms*2 + (lb>>1)) & 3)*16 + (n&15))*8 + 4*(lb&1);
          s16x4 o;
          #pragma unroll
          for (int r = 0; r < 4; ++r) o[r] = f2bf(acc[ms][ns][r] + bm[ms*4+r]);
          *(s16x4*)(outT + a) = o;
        }
    } else {
      short* vout = (short*)outp3 + (size_t)b * 524288;    // frag tiles
      float bn[NSF];
      #pragma unroll
      for (int ns = 0; ns < NSF; ++ns){
        const int o = no + ns*16 + lm;
        bn[ns] = bias[192*((o>>6)&7) + 128 + (o&63)];
      }
      #pragma unroll
      for (int ms = 0; ms < 4; ++ms)
        #pragma unroll
        for (int ns = 0; ns < NSF; ++ns){
          const int m = mo + ms*16 + 4*lb;                 // r=0 row; s = m+r
          const int n = no + ns*16 + lm;
          const int h = (n >> 6) & 7, c = n & 63;
          const size_t a = ((size_t)h*128 + (c>>4)*32 + (m>>5))*512
                         + (((m>>2)&3)*16 + (c&15))*8 + ((m>>4)&1)*4;
          s16x4 o;
          #pragma unroll
          for (int r = 0; r < 4; ++r) o[r] = f2bf(acc[ms][ns][r] + bn[ns]);
          *(s16x4*)(vout + a) = o;
        }
    }
  } else {
    // proj: LDS-transposed epilogue -> coalesced float4 resid-add/store
    __syncthreads();                          // staging reads done
    float* Lf = (float*)smem;                 // [128][68] f32
    #pragma unroll
    for (int ms = 0; ms < 4; ++ms)
      #pragma unroll
      for (int ns = 0; ns < NSF; ++ns)
        #pragma unroll
        for (int r = 0; r < 4; ++r)
          Lf[(wm*64 + ms*16 + 4*lb + r)*68 + wn*32 + ns*16 + lm] = acc[ms][ns][r];
    __syncthreads();
    float* out = (float*)outp + (size_t)b * 524288;
    const float* xr2 = resid + (size_t)b * 524288;
    #pragma unroll
    for (int p = 0; p < 8; ++p){
      const int row = p*16 + (tid >> 4);
      const int c4  = (tid & 15) * 4;
      float4 v = *(const float4*)&Lf[row*68 + c4];
      const float bs = bias[m0 + row];
      const size_t off = (size_t)(m0 + row)*1024 + n0 + c4;
      float4 rv = *(const float4*)(xr2 + off);
      float4 ov = make_float4(v.x+bs+rv.x, v.y+bs+rv.y, v.z+bs+rv.z, v.w+bs+rv.w);
      *(float4*)(out + off) = ov;
    }
  }
}

// ---------------------------------------------------------------------------
// Attention v12: barrier-free, ONE block per CU. 256 blocks x 512 thr;
// bid = bh + 64*tc (tc 0..3; bh%8 -> XCD). Wave w (0..7) owns 32 t-cols of a
// 256-t chunk; all 8 waves share one K/V stream (L1 dedup). Q/K/V frags ALL
// single coalesced 1KB b128 loads (frag-tile layouts). K ping-pong prefetch
// hides L2 latency. exp2 direct (shift-invariant, |s|<~10 << 125). lsum as
// f32x4 per tb (4 independent add chains), reduced once at end.
__global__ __launch_bounds__(512) void attn12_kernel(const short* __restrict__ qbuf,
    const short* __restrict__ kbuf, const short* __restrict__ vbuf,
    short* __restrict__ attT){
  const int bid = blockIdx.x;
  const int bh = bid & 63, tc = bid >> 6;
  const int b = bh >> 3, h = bh & 7;
  const int tid = threadIdx.x;
  const int lane = tid & 63, w = tid >> 6;
  const int lm = lane & 15, lb = lane >> 4;
  const int t0 = tc * 256;

  const short* qb = qbuf + (size_t)b*524288 + (size_t)h*65536 + lane*8;
  const short* kb = kbuf + (size_t)b*524288 + (size_t)h*65536 + lane*8;
  const short* vb = vbuf + (size_t)b*524288 + (size_t)h*65536 + lane*8;

  __shared__ short Tl[256*72];       // epilogue transpose only (36864 B)

  // Q frags: coalesced 1KB tile loads (tile = (t>>4)*2 + ks)
  s16x8 qf[2][2];
  #pragma unroll
  for (int tb = 0; tb < 2; ++tb)
    #pragma unroll
    for (int ks = 0; ks < 2; ++ks)
      qf[tb][ks] = *(const s16x8*)(qb +
          (size_t)((((t0 >> 4) + w*2 + tb)*2) + ks)*512);

  f32x4 of[2][4] = {};
  f32x4 lacc[2] = {};                // 4 independent partial-sum chains per tb
  s16x8 kA[2][4], kB[2][4];

  auto load_k = [&](int it, s16x8 (&kf)[2][4]){
    #pragma unroll
    for (int ks = 0; ks < 2; ++ks)
      #pragma unroll
      for (int ms = 0; ms < 4; ++ms)
        kf[ks][ms] = *(const s16x8*)(kb + (size_t)((it*4 + ms)*2 + ks)*512);
  };

  auto body = [&](int it, s16x8 (&kcur)[2][4], s16x8 (&knxt)[2][4]){
    // V frags for this iter (consumed last -> latency hidden under QK+exp)
    s16x8 vf[2][4];
    #pragma unroll
    for (int ks2 = 0; ks2 < 2; ++ks2)
      #pragma unroll
      for (int cs = 0; cs < 4; ++cs)
        vf[ks2][cs] = *(const s16x8*)(vb + (size_t)(cs*32 + it*2 + ks2)*512);

    // prefetch next iter's K frags (consumed next body -> latency hidden)
    if (it + 1 < 16) load_k(it + 1, knxt);

    // QK^T: S'[s][t]
    f32x4 sf[2][4];
    #pragma unroll
    for (int tb = 0; tb < 2; ++tb)
      #pragma unroll
      for (int ms = 0; ms < 4; ++ms) sf[tb][ms] = 0.f;
    #pragma unroll
    for (int ks = 0; ks < 2; ++ks)
      #pragma unroll
      for (int ms = 0; ms < 4; ++ms){
        sf[0][ms] = mfma_bf16_16x16x32(kcur[ks][ms], qf[0][ks], sf[0][ms]);
        sf[1][ms] = mfma_bf16_16x16x32(kcur[ks][ms], qf[1][ks], sf[1][ms]);
      }

    // p = exp2(s) directly; lsum in 4 independent chains (r-indexed, unrolled)
    s16x8 pbf[2][2];
    #pragma unroll
    for (int tb = 0; tb < 2; ++tb)
      #pragma unroll
      for (int ms = 0; ms < 4; ++ms)
        #pragma unroll
        for (int r = 0; r < 4; ++r){
          const float e = __builtin_amdgcn_exp2f(sf[tb][ms][r]);
          lacc[tb][r] += e;
          pbf[tb][ms >> 1][(ms & 1)*4 + r] = f2bf(e);
        }

    // PV: D[c][t] = mfma(A=V frag, B=P' in-lane)
    #pragma unroll
    for (int ks2 = 0; ks2 < 2; ++ks2)
      #pragma unroll
      for (int cs = 0; cs < 4; ++cs){
        of[0][cs] = mfma_bf16_16x16x32(vf[ks2][cs], pbf[0][ks2], of[0][cs]);
        of[1][cs] = mfma_bf16_16x16x32(vf[ks2][cs], pbf[1][ks2], of[1][cs]);
      }
  };

  load_k(0, kA);
  for (int it2 = 0; it2 < 16; it2 += 2){
    body(it2,     kA, kB);
    body(it2 + 1, kB, kA);
  }

  // reduce partial sums: 4 chains -> scalar, then across the 4 lb groups
  float lsum[2];
  #pragma unroll
  for (int tb = 0; tb < 2; ++tb){
    lsum[tb] = (lacc[tb][0] + lacc[tb][1]) + (lacc[tb][2] + lacc[tb][3]);
    lsum[tb] += __shfl_xor(lsum[tb], 16, 64);
    lsum[tb] += __shfl_xor(lsum[tb], 32, 64);
  }
  const float inv0 = 1.f / lsum[0], inv1 = 1.f / lsum[1];

  // transpose [c][t] regs -> attT[b][t][c] via LDS
  #pragma unroll
  for (int tb = 0; tb < 2; ++tb)
    #pragma unroll
    for (int cs = 0; cs < 4; ++cs){
      s16x4 o;
      #pragma unroll
      for (int r = 0; r < 4; ++r)
        o[r] = f2bf(of[tb][cs][r] * (tb ? inv1 : inv0));
      *(s16x4*)&Tl[(w*32 + tb*16 + lm)*72 + cs*16 + 4*lb] = o;
    }
  __syncthreads();
  short* outb = attT + (size_t)b*524288 + (size_t)t0*512 + h*64;
  #pragma unroll
  for (int i = 0; i < 4; ++i){
    const int g = tid + i*512, r = g >> 3, c8 = g & 7;
    *(uint4*)(outb + (size_t)r*512 + c8*8) = *(const uint4*)&Tl[r*72 + c8*8];
  }
}

// ---------------------------------------------------------------------------
extern "C" void kernel_launch(void* const* d_in, const int* in_sizes, int n_in,
                              void* d_out, int out_size, void* d_ws, size_t ws_size,
                              hipStream_t stream){
  const float* x      = (const float*)d_in[0];
  const float* norm_w = (const float*)d_in[1];
  const float* norm_b = (const float*)d_in[2];
  const float* qkv_w  = (const float*)d_in[3];
  const float* qkv_b  = (const float*)d_in[4];
  const float* proj_w = (const float*)d_in[5];
  const float* proj_b = (const float*)d_in[6];

  char* ws = (char*)d_ws;
  float2* stats = (float2*)(ws);                    // 4 KB
  short*  xnT   = (short*)(ws + 4096);              // 8 MiB
  short*  qwb   = (short*)(ws + 8392704);           // 1.5 MiB
  short*  pwb   = (short*)(ws + 9965568);           // 0.5 MiB
  short*  qbuf  = (short*)(ws + 10489856);          // 8 MiB (frag tiles)
  short*  kbuf  = (short*)(ws + 18878464);          // 8 MiB (frag tiles)
  short*  vbuf  = (short*)(ws + 27267072);          // 8 MiB (frag tiles)
  short*  attT  = (short*)(ws + 35655680);          // 8 MiB

  prep_kernel<<<dim3(768), dim3(256), 0, stream>>>(x, stats, qkv_w, proj_w, qwb, pwb);
  gn_norm_t_kernel<<<dim3(16, 8), dim3(256), 0, stream>>>(x, norm_w, norm_b, stats, xnT);
  gemm_k512<0,128><<<dim3(8, 8, 12), dim3(256), 0, stream>>>(qwb, xnT, qkv_b, nullptr,
      (void*)qbuf, (void*)kbuf, (void*)vbuf);
  attn12_kernel<<<dim3(256), dim3(512), 0, stream>>>(qbuf, kbuf, vbuf, attT);
  gemm_k512<2,64><<<dim3(8, 4, 16), dim3(256), 0, stream>>>(pwb, attT, proj_b, x,
      d_out, nullptr, nullptr);
}

// Round 15
// 74.053 us; speedup vs baseline: 1.2597x; 1.1092x over previous
//
#include <hip/hip_runtime.h>
#include <stdint.h>

// ---------------------------------------------------------------------------
// AttentionBlock: GroupNorm(32) -> qkv 1x1 -> 8-head attention (T=1024,ch=64)
//                 -> proj 1x1 + residual.  B=8, C=512, T=1024. fp32 I/O,
//                 bf16 MFMA internally.  4 kernels:
//   gn_fused: blocks 0..255 = per-(b,group) stats + normalize + LDS-transpose
//             -> bf16 xnT[b][t][c] (one x pass instead of two);
//             blocks 256..767 = weight fp32->bf16 cvt.
//   gemmQKV: fused; Q,K = D[c][t] = W x xnT -> frag-tiles (r-contiguous
//            s16x4 stores); V = D[t][o'] -> frag-tiles (s16x4 stores).
//   attn   : barrier-free flash: 256 blk x 8 waves x 32t, 1 blk/CU, shared
//            K/V stream, K ping-pong prefetch; Q/K/V frags ALL coalesced
//            1KB b128 loads; exp2 direct (no max: |s|<~10, shift-invariant);
//            lsum as f32x4 (4 indep add chains).
//   proj   : D[o][t] = Wp x att + bias + x -> d_out; LDS-transposed epilogue.
// Frag-tile layout (1KB): addr = tile*512 + lane*8 + j; A/B share slot->k map
//   so the HW k-permutation cancels.
// Lessons: R4 spills; R5 LDS>64K; R7/R12 split adds traffic; R8 strided
//   reads; R9-R14 scattered 2B stores all fixed; R13 attn scheduling null;
//   R15 fuses stats+norm (one x HBM pass, one fewer launch).
// ---------------------------------------------------------------------------

typedef float  f32x4  __attribute__((ext_vector_type(4)));
typedef short  s16x4  __attribute__((ext_vector_type(4)));
typedef short  s16x8  __attribute__((ext_vector_type(8)));
typedef __bf16 bf16x8 __attribute__((ext_vector_type(8)));

#define QK_SCALE 0.4246609f   // sqrt(0.125 * log2(e))

__device__ __forceinline__ f32x4 mfma_bf16_16x16x32(s16x8 a, s16x8 b, f32x4 c){
  return __builtin_amdgcn_mfma_f32_16x16x32_bf16(
      __builtin_bit_cast(bf16x8, a), __builtin_bit_cast(bf16x8, b), c, 0, 0, 0);
}

__device__ __forceinline__ short f2bf(float v){
  return __builtin_bit_cast(short, static_cast<__bf16>(v));
}

// async global->LDS, 16B per lane; dest = firstlane-base + lane*16 (linear)
__device__ __forceinline__ void gload16(const void* g, void* l){
  __builtin_amdgcn_global_load_lds(
      (const __attribute__((address_space(1))) void*)g,
      (__attribute__((address_space(3))) void*)l, 16, 0, 0);
}

// ---------------------------------------------------------------------------
// gn_fused: blocks 0..255 = (b,g) stats + normalize + transpose; 256..767 cvt.
// Stats pass: 64KB coalesced read + tree reduce. Normalize pass: re-read
// (L2-resident) in 16 tiles of [16ch][64t], LDS transpose, 32B-segment writes.
__global__ __launch_bounds__(256) void gn_fused_kernel(const float* __restrict__ x,
    const float* __restrict__ w, const float* __restrict__ bia,
    short* __restrict__ xnT, const float* __restrict__ qkv_w,
    const float* __restrict__ proj_w, short* __restrict__ qwb,
    short* __restrict__ pwb){
  const int tid = threadIdx.x;
  if (blockIdx.x < 256){
    __shared__ float ss[256], sq[256];
    __shared__ float scs[16], shs[16];
    __shared__ short L[16*68];
    const int bg = blockIdx.x;            // b = bg>>5, g = bg&31
    const int b = bg >> 5, g = bg & 31;
    const float* xb = x + (size_t)bg * 16384;   // [16ch][1024t]
    // pass 1: stats
    float s = 0.f, q = 0.f;
    #pragma unroll
    for (int i = 0; i < 16; ++i){
      float4 v = ((const float4*)xb)[tid + i*256];
      s += v.x + v.y + v.z + v.w;
      q += v.x*v.x + v.y*v.y + v.z*v.z + v.w*v.w;
    }
    ss[tid] = s; sq[tid] = q;
    __syncthreads();
    for (int off = 128; off > 0; off >>= 1){
      if (tid < off){ ss[tid] += ss[tid+off]; sq[tid] += sq[tid+off]; }
      __syncthreads();
    }
    if (tid < 16){
      const float mu  = ss[0] * (1.f/16384.f);
      const float var = sq[0] * (1.f/16384.f) - mu*mu;   // biased
      const float rstd = rsqrtf(var + 1e-5f);
      const int ch = g*16 + tid;
      const float sc = rstd * w[ch];
      scs[tid] = sc;
      shs[tid] = bia[ch] - mu * sc;
    }
    __syncthreads();
    // pass 2: 16 tiles of [16ch][64t]: normalize -> LDS -> transposed write
    short* ob = xnT + (size_t)b * 524288 + g*16;
    for (int cc = 0; cc < 16; ++cc){
      const int row = tid >> 4, t4 = (tid & 15) * 4;
      float4 v = *(const float4*)(xb + (size_t)row*1024 + cc*64 + t4);
      const float sc = scs[row], sh = shs[row];
      s16x4 o;
      o[0]=f2bf(v.x*sc+sh); o[1]=f2bf(v.y*sc+sh); o[2]=f2bf(v.z*sc+sh); o[3]=f2bf(v.w*sc+sh);
      *(s16x4*)&L[row*68 + t4] = o;
      __syncthreads();
      const int tl = tid >> 2, c4 = (tid & 3) * 4;
      s16x4 t;
      #pragma unroll
      for (int j = 0; j < 4; ++j) t[j] = L[(c4 + j)*68 + tl];
      *(s16x4*)(ob + (size_t)(cc*64 + tl)*512 + c4) = t;
      __syncthreads();
    }
  } else {
    const int i = (blockIdx.x - 256)*256 + tid;   // 0..131071
    const float* in; short* out; float s;
    if (i < 98304){
      in = qkv_w + (size_t)i*8; out = qwb + (size_t)i*8;
      s = (((i >> 6) % 192) < 128) ? QK_SCALE : 1.f;     // q,k rows pre-scaled
    } else {
      const int j = i - 98304;
      in = proj_w + (size_t)j*8; out = pwb + (size_t)j*8;
      s = 1.f;
    }
    const float4* p = (const float4*)in;
    float4 a = p[0], b2 = p[1];
    s16x8 o;
    o[0]=f2bf(a.x*s);  o[1]=f2bf(a.y*s);  o[2]=f2bf(a.z*s);  o[3]=f2bf(a.w*s);
    o[4]=f2bf(b2.x*s); o[5]=f2bf(b2.y*s); o[6]=f2bf(b2.z*s); o[7]=f2bf(b2.w*s);
    *(s16x8*)out = o;
  }
}

// ---------------------------------------------------------------------------
// Unified K=512 GEMM, 128xNB tile, BK=32, 4 waves (2x2).
// Staging: global_load_lds w=16 into linear [row][32] tiles; XOR swizzle
// slot = lb ^ ((row>>1)&3) on reads, source chunk (c&3)^((c>>3)&3) on stage.
// MODE 0 (NB=128, fused QKV), part = z>>2:
//   part 0 (Q), part 1 (K): D[c][t] = W x xnT. m0=(z&3)*128 (channel),
//     n0=y*128 (t). -> frag-tiles, r-contiguous s16x4 stores.
//   part 2 (V): D[t][o'] -> vbuf frag-tiles, s16x4 stores.
// MODE 2 (NB=64): A=Wp o-rows, B=attT t-rows -> f32 out via LDS-transposed
//   epilogue: 256B-coalesced float4 resid-add/store.
template<int MODE, int NB>
__global__ __launch_bounds__(256) void gemm_k512(const short* __restrict__ W,
    const short* __restrict__ act, const float* __restrict__ bias,
    const float* __restrict__ resid, void* __restrict__ outp,
    void* __restrict__ outp2, void* __restrict__ outp3){
  constexpr int NSF = NB / 32;      // n-frags per wave
  constexpr int SMEM_BYTES = (MODE == 2) ? 34816 : 32768;
  const int b  = blockIdx.x;
  const int tid  = threadIdx.x;
  const int lane = tid & 63, w = tid >> 6;
  const int wm = w >> 1, wn = w & 1;
  const int lm = lane & 15, lb = lane >> 4;
  const int xr = (lm >> 1) & 3;     // row-swizzle term for frag reads

  int part, m0, n0;
  if constexpr (MODE == 0){
    const int z = blockIdx.z;
    part = z >> 2;                  // 0=Q 1=K 2=V
    if (part < 2){ m0 = (z & 3)*128; n0 = blockIdx.y*128; }
    else         { m0 = blockIdx.y*128; n0 = 1024 + (z & 3)*128; }
  } else {
    part = 0; m0 = blockIdx.y*128; n0 = blockIdx.z*NB;
  }

  __shared__ __align__(16) char smem[SMEM_BYTES];
  short* Asb = (short*)smem;                 // [2][128*32]
  short* Bsb = (short*)(smem + 16384);       // [2][NB*32]

  const short* actb = act + (size_t)b * 524288;

  auto arow = [&](int r) -> const short* {
    if constexpr (MODE == 0){
      if (part < 2){
        const int m = m0 + r;
        return W + (size_t)(192*(m>>6) + part*64 + (m&63)) * 512;
      }
      return actb + (size_t)(m0 + r) * 512;
    } else {
      return W + (size_t)(m0 + r) * 512;
    }
  };
  auto brow = [&](int r) -> const short* {
    if constexpr (MODE == 0){
      if (part < 2) return actb + (size_t)(n0 + r) * 512;
      const int o = n0 + r;                   // 1024..1535
      return W + (size_t)(192*((o>>6)&7) + 128 + (o&63)) * 512;
    } else {
      return actb + (size_t)(n0 + r) * 512;
    }
  };

  // stage K-tile t into buf: async gload_lds; source chunk pre-swizzled
  auto stage = [&](int t, int buf){
    const int k0 = t * 32;
    #pragma unroll
    for (int i = 0; i < 2; ++i){
      const int c = tid + i*256;
      const int r = c >> 2, sj = (c & 3) ^ ((c >> 3) & 3);
      gload16(arow(r) + k0 + sj*8, Asb + buf*4096 + (c>>2)*32 + (c&3)*8);
    }
    #pragma unroll
    for (int i = 0; i < NB/64; ++i){
      const int c = tid + i*256;
      const int r = c >> 2, sj = (c & 3) ^ ((c >> 3) & 3);
      gload16(brow(r) + k0 + sj*8, Bsb + buf*(NB*32) + (c>>2)*32 + (c&3)*8);
    }
  };

  f32x4 acc[4][NSF] = {};
  stage(0, 0);

  for (int t = 0; t < 16; ++t){
    __syncthreads();                 // waits vmcnt(0) for prior stage
    if (t + 1 < 16) stage(t + 1, (t + 1) & 1);
    const int buf = t & 1;

    s16x8 af[4], bfr[NSF];
    #pragma unroll
    for (int ms = 0; ms < 4; ++ms){
      const int row = wm*64 + ms*16 + lm;
      af[ms] = *(const s16x8*)(Asb + buf*4096 + row*32 + ((lb ^ xr) << 3));
    }
    #pragma unroll
    for (int ns = 0; ns < NSF; ++ns){
      const int row = wn*(NB/2) + ns*16 + lm;
      bfr[ns] = *(const s16x8*)(Bsb + buf*(NB*32) + row*32 + ((lb ^ xr) << 3));
    }
    #pragma unroll
    for (int ns = 0; ns < NSF; ++ns)
      #pragma unroll
      for (int ms = 0; ms < 4; ++ms)
        acc[ms][ns] = mfma_bf16_16x16x32(af[ms], bfr[ns], acc[ms][ns]);
  }

  // C/D: col = lane&15, row = 4*(lane>>4) + reg   (m89)
  const int mo = m0 + wm*64, no = n0 + wn*(NB/2);
  if constexpr (MODE == 0){
    if (part < 2){
      // Q/K in D[c][t] orientation: m = channel, n = t/s; r-contiguous tiles.
      short* outT = (short*)(part == 0 ? outp : outp2) + (size_t)b * 524288;
      const int hh = m0/64 + wm;                           // m>>6, wave-uniform
      float bm[16];
      #pragma unroll
      for (int ms = 0; ms < 4; ++ms)
        #pragma unroll
        for (int r = 0; r < 4; ++r){
          const int m = mo + ms*16 + 4*lb + r;
          bm[ms*4+r] = QK_SCALE * bias[192*(m>>6) + part*64 + (m&63)];
        }
      #pragma unroll
      for (int ms = 0; ms < 4; ++ms)
        #pragma unroll
        for (int ns = 0; ns < NSF; ++ns){
          const int n = no + ns*16 + lm;                   // t (attn s/t)
          const size_t a = ((size_t)hh*128 + (n>>4)*2 + (ms>>1))*512
                         + (((ms*2 + (lb>>1)) & 3)*16 + (n&15))*8 + 4*(lb&1);
          s16x4 o;
          #pragma unroll
          for (int r = 0; r < 4; ++r) o[r] = f2bf(acc[ms][ns][r] + bm[ms*4+r]);
          *(s16x4*)(outT + a) = o;
        }
    } else {
      short* vout = (short*)outp3 + (size_t)b * 524288;    // frag tiles
      float bn[NSF];
      #pragma unroll
      for (int ns = 0; ns < NSF; ++ns){
        const int o = no + ns*16 + lm;
        bn[ns] = bias[192*((o>>6)&7) + 128 + (o&63)];
      }
      #pragma unroll
      for (int ms = 0; ms < 4; ++ms)
        #pragma unroll
        for (int ns = 0; ns < NSF; ++ns){
          const int m = mo + ms*16 + 4*lb;                 // r=0 row; s = m+r
          const int n = no + ns*16 + lm;
          const int h = (n >> 6) & 7, c = n & 63;
          const size_t a = ((size_t)h*128 + (c>>4)*32 + (m>>5))*512
                         + (((m>>2)&3)*16 + (c&15))*8 + ((m>>4)&1)*4;
          s16x4 o;
          #pragma unroll
          for (int r = 0; r < 4; ++r) o[r] = f2bf(acc[ms][ns][r] + bn[ns]);
          *(s16x4*)(vout + a) = o;
        }
    }
  } else {
    // proj: LDS-transposed epilogue -> coalesced float4 resid-add/store
    __syncthreads();                          // staging reads done
    float* Lf = (float*)smem;                 // [128][68] f32
    #pragma unroll
    for (int ms = 0; ms < 4; ++ms)
      #pragma unroll
      for (int ns = 0; ns < NSF; ++ns)
        #pragma unroll
        for (int r = 0; r < 4; ++r)
          Lf[(wm*64 + ms*16 + 4*lb + r)*68 + wn*32 + ns*16 + lm] = acc[ms][ns][r];
    __syncthreads();
    float* out = (float*)outp + (size_t)b * 524288;
    const float* xr2 = resid + (size_t)b * 524288;
    #pragma unroll
    for (int p = 0; p < 8; ++p){
      const int row = p*16 + (tid >> 4);
      const int c4  = (tid & 15) * 4;
      float4 v = *(const float4*)&Lf[row*68 + c4];
      const float bs = bias[m0 + row];
      const size_t off = (size_t)(m0 + row)*1024 + n0 + c4;
      float4 rv = *(const float4*)(xr2 + off);
      float4 ov = make_float4(v.x+bs+rv.x, v.y+bs+rv.y, v.z+bs+rv.z, v.w+bs+rv.w);
      *(float4*)(out + off) = ov;
    }
  }
}

// ---------------------------------------------------------------------------
// Attention v12 (R14, unchanged): barrier-free, ONE block per CU. 256 blocks
// x 512 thr; bid = bh + 64*tc (bh%8 -> XCD). Wave w owns 32 t-cols of a 256-t
// chunk; all 8 waves share one K/V stream (L1 dedup). Q/K/V frags ALL single
// coalesced 1KB b128 loads. K ping-pong prefetch. exp2 direct (shift-
// invariant, |s|<~10 << 125). lsum as f32x4 (4 indep chains), reduced once.
__global__ __launch_bounds__(512) void attn12_kernel(const short* __restrict__ qbuf,
    const short* __restrict__ kbuf, const short* __restrict__ vbuf,
    short* __restrict__ attT){
  const int bid = blockIdx.x;
  const int bh = bid & 63, tc = bid >> 6;
  const int b = bh >> 3, h = bh & 7;
  const int tid = threadIdx.x;
  const int lane = tid & 63, w = tid >> 6;
  const int lm = lane & 15, lb = lane >> 4;
  const int t0 = tc * 256;

  const short* qb = qbuf + (size_t)b*524288 + (size_t)h*65536 + lane*8;
  const short* kb = kbuf + (size_t)b*524288 + (size_t)h*65536 + lane*8;
  const short* vb = vbuf + (size_t)b*524288 + (size_t)h*65536 + lane*8;

  __shared__ short Tl[256*72];       // epilogue transpose only (36864 B)

  // Q frags: coalesced 1KB tile loads (tile = (t>>4)*2 + ks)
  s16x8 qf[2][2];
  #pragma unroll
  for (int tb = 0; tb < 2; ++tb)
    #pragma unroll
    for (int ks = 0; ks < 2; ++ks)
      qf[tb][ks] = *(const s16x8*)(qb +
          (size_t)((((t0 >> 4) + w*2 + tb)*2) + ks)*512);

  f32x4 of[2][4] = {};
  f32x4 lacc[2] = {};                // 4 independent partial-sum chains per tb
  s16x8 kA[2][4], kB[2][4];

  auto load_k = [&](int it, s16x8 (&kf)[2][4]){
    #pragma unroll
    for (int ks = 0; ks < 2; ++ks)
      #pragma unroll
      for (int ms = 0; ms < 4; ++ms)
        kf[ks][ms] = *(const s16x8*)(kb + (size_t)((it*4 + ms)*2 + ks)*512);
  };

  auto body = [&](int it, s16x8 (&kcur)[2][4], s16x8 (&knxt)[2][4]){
    // V frags for this iter (consumed last -> latency hidden under QK+exp)
    s16x8 vf[2][4];
    #pragma unroll
    for (int ks2 = 0; ks2 < 2; ++ks2)
      #pragma unroll
      for (int cs = 0; cs < 4; ++cs)
        vf[ks2][cs] = *(const s16x8*)(vb + (size_t)(cs*32 + it*2 + ks2)*512);

    // prefetch next iter's K frags (consumed next body -> latency hidden)
    if (it + 1 < 16) load_k(it + 1, knxt);

    // QK^T: S'[s][t]
    f32x4 sf[2][4];
    #pragma unroll
    for (int tb = 0; tb < 2; ++tb)
      #pragma unroll
      for (int ms = 0; ms < 4; ++ms) sf[tb][ms] = 0.f;
    #pragma unroll
    for (int ks = 0; ks < 2; ++ks)
      #pragma unroll
      for (int ms = 0; ms < 4; ++ms){
        sf[0][ms] = mfma_bf16_16x16x32(kcur[ks][ms], qf[0][ks], sf[0][ms]);
        sf[1][ms] = mfma_bf16_16x16x32(kcur[ks][ms], qf[1][ks], sf[1][ms]);
      }

    // p = exp2(s) directly; lsum in 4 independent chains (r-indexed, unrolled)
    s16x8 pbf[2][2];
    #pragma unroll
    for (int tb = 0; tb < 2; ++tb)
      #pragma unroll
      for (int ms = 0; ms < 4; ++ms)
        #pragma unroll
        for (int r = 0; r < 4; ++r){
          const float e = __builtin_amdgcn_exp2f(sf[tb][ms][r]);
          lacc[tb][r] += e;
          pbf[tb][ms >> 1][(ms & 1)*4 + r] = f2bf(e);
        }

    // PV: D[c][t] = mfma(A=V frag, B=P' in-lane)
    #pragma unroll
    for (int ks2 = 0; ks2 < 2; ++ks2)
      #pragma unroll
      for (int cs = 0; cs < 4; ++cs){
        of[0][cs] = mfma_bf16_16x16x32(vf[ks2][cs], pbf[0][ks2], of[0][cs]);
        of[1][cs] = mfma_bf16_16x16x32(vf[ks2][cs], pbf[1][ks2], of[1][cs]);
      }
  };

  load_k(0, kA);
  for (int it2 = 0; it2 < 16; it2 += 2){
    body(it2,     kA, kB);
    body(it2 + 1, kB, kA);
  }

  // reduce partial sums: 4 chains -> scalar, then across the 4 lb groups
  float lsum[2];
  #pragma unroll
  for (int tb = 0; tb < 2; ++tb){
    lsum[tb] = (lacc[tb][0] + lacc[tb][1]) + (lacc[tb][2] + lacc[tb][3]);
    lsum[tb] += __shfl_xor(lsum[tb], 16, 64);
    lsum[tb] += __shfl_xor(lsum[tb], 32, 64);
  }
  const float inv0 = 1.f / lsum[0], inv1 = 1.f / lsum[1];

  // transpose [c][t] regs -> attT[b][t][c] via LDS
  #pragma unroll
  for (int tb = 0; tb < 2; ++tb)
    #pragma unroll
    for (int cs = 0; cs < 4; ++cs){
      s16x4 o;
      #pragma unroll
      for (int r = 0; r < 4; ++r)
        o[r] = f2bf(of[tb][cs][r] * (tb ? inv1 : inv0));
      *(s16x4*)&Tl[(w*32 + tb*16 + lm)*72 + cs*16 + 4*lb] = o;
    }
  __syncthreads();
  short* outb = attT + (size_t)b*524288 + (size_t)t0*512 + h*64;
  #pragma unroll
  for (int i = 0; i < 4; ++i){
    const int g = tid + i*512, r = g >> 3, c8 = g & 7;
    *(uint4*)(outb + (size_t)r*512 + c8*8) = *(const uint4*)&Tl[r*72 + c8*8];
  }
}

// ---------------------------------------------------------------------------
extern "C" void kernel_launch(void* const* d_in, const int* in_sizes, int n_in,
                              void* d_out, int out_size, void* d_ws, size_t ws_size,
                              hipStream_t stream){
  const float* x      = (const float*)d_in[0];
  const float* norm_w = (const float*)d_in[1];
  const float* norm_b = (const float*)d_in[2];
  const float* qkv_w  = (const float*)d_in[3];
  const float* qkv_b  = (const float*)d_in[4];
  const float* proj_w = (const float*)d_in[5];
  const float* proj_b = (const float*)d_in[6];

  char* ws = (char*)d_ws;
  short*  xnT   = (short*)(ws + 4096);              // 8 MiB
  short*  qwb   = (short*)(ws + 8392704);           // 1.5 MiB
  short*  pwb   = (short*)(ws + 9965568);           // 0.5 MiB
  short*  qbuf  = (short*)(ws + 10489856);          // 8 MiB (frag tiles)
  short*  kbuf  = (short*)(ws + 18878464);          // 8 MiB (frag tiles)
  short*  vbuf  = (short*)(ws + 27267072);          // 8 MiB (frag tiles)
  short*  attT  = (short*)(ws + 35655680);          // 8 MiB

  gn_fused_kernel<<<dim3(768), dim3(256), 0, stream>>>(x, norm_w, norm_b, xnT,
      qkv_w, proj_w, qwb, pwb);
  gemm_k512<0,128><<<dim3(8, 8, 12), dim3(256), 0, stream>>>(qwb, xnT, qkv_b, nullptr,
      (void*)qbuf, (void*)kbuf, (void*)vbuf);
  attn12_kernel<<<dim3(256), dim3(512), 0, stream>>>(qbuf, kbuf, vbuf, attT);
  gemm_k512<2,64><<<dim3(8, 4, 16), dim3(256), 0, stream>>>(pwb, attT, proj_b, x,
      d_out, nullptr, nullptr);
}

// Round 16
// 68.471 us; speedup vs baseline: 1.3624x; 1.0815x over previous
//
#include <hip/hip_runtime.h>
#include <stdint.h>

// ---------------------------------------------------------------------------
// AttentionBlock: GroupNorm(32) -> qkv 1x1 -> 8-head attention (T=1024,ch=64)
//                 -> proj 1x1 + residual.  B=8, C=512, T=1024. fp32 I/O,
//                 bf16 MFMA internally.  4 kernels:
//   gn_fused: blocks 0..255 = per-(b,group) stats + normalize + transpose,
//             x kept IN REGISTERS across both passes (one HBM read, ONE
//             barrier for the transpose); blocks 256..767 = weight cvt.
//   gemmQKV: fused; Q,K = D[c][t] = W x xnT -> frag-tiles (r-contiguous
//            s16x4 stores); V = D[t][o'] -> frag-tiles (s16x4 stores).
//   attn   : barrier-free flash: 256 blk x 8 waves x 32t, 1 blk/CU, shared
//            K/V stream, K ping-pong prefetch; Q/K/V frags ALL coalesced
//            1KB b128 loads; exp2 direct (no max: |s|<~10, shift-invariant);
//            lsum as f32x4 (4 indep add chains).
//   proj   : D[o][t] = Wp x att + bias + x -> d_out; LDS-transposed epilogue
//            with residual loads hoisted before the barrier (T14).
// Frag-tile layout (1KB): addr = tile*512 + lane*8 + j; A/B share slot->k map
//   so the HW k-permutation cancels.
// Lessons: R4 spills; R5 LDS>64K; R7/R12 split adds traffic; R8 strided
//   reads; R9-R14 scattered 2B stores fixed; R13 attn scheduling null;
//   R15 one-x-pass fusion; R16 reg-resident gn + hoisted proj residual.
// ---------------------------------------------------------------------------

typedef float  f32x4  __attribute__((ext_vector_type(4)));
typedef short  s16x4  __attribute__((ext_vector_type(4)));
typedef short  s16x8  __attribute__((ext_vector_type(8)));
typedef __bf16 bf16x8 __attribute__((ext_vector_type(8)));

#define QK_SCALE 0.4246609f   // sqrt(0.125 * log2(e))

__device__ __forceinline__ f32x4 mfma_bf16_16x16x32(s16x8 a, s16x8 b, f32x4 c){
  return __builtin_amdgcn_mfma_f32_16x16x32_bf16(
      __builtin_bit_cast(bf16x8, a), __builtin_bit_cast(bf16x8, b), c, 0, 0, 0);
}

__device__ __forceinline__ short f2bf(float v){
  return __builtin_bit_cast(short, static_cast<__bf16>(v));
}

// async global->LDS, 16B per lane; dest = firstlane-base + lane*16 (linear)
__device__ __forceinline__ void gload16(const void* g, void* l){
  __builtin_amdgcn_global_load_lds(
      (const __attribute__((address_space(1))) void*)g,
      (__attribute__((address_space(3))) void*)l, 16, 0, 0);
}

// ---------------------------------------------------------------------------
// gn_fused: blocks 0..255 = (b,g) stats+normalize+transpose (reg-resident x);
//           blocks 256..767 = weight cvt.
// Thread tid holds channel i (i=0..15) at t = tid*4..tid*4+3 (float4 v[i]).
__global__ __launch_bounds__(256) void gn_fused_kernel(const float* __restrict__ x,
    const float* __restrict__ w, const float* __restrict__ bia,
    short* __restrict__ xnT, const float* __restrict__ qkv_w,
    const float* __restrict__ proj_w, short* __restrict__ qwb,
    short* __restrict__ pwb){
  const int tid = threadIdx.x;
  if (blockIdx.x < 256){
    __shared__ float ss[256], sq[256];
    __shared__ float scs[16], shs[16];
    __shared__ short L[16*1032];               // [ch][1024 t] pad->1032
    const int bg = blockIdx.x;
    const int b = bg >> 5, g = bg & 31;
    const float* xb = x + (size_t)bg * 16384;  // [16ch][1024t]
    // pass 1: load once, keep in regs, accumulate stats
    float4 v[16];
    float s = 0.f, q = 0.f;
    #pragma unroll
    for (int i = 0; i < 16; ++i){
      v[i] = ((const float4*)xb)[tid + i*256];
      s += v[i].x + v[i].y + v[i].z + v[i].w;
      q += v[i].x*v[i].x + v[i].y*v[i].y + v[i].z*v[i].z + v[i].w*v[i].w;
    }
    ss[tid] = s; sq[tid] = q;
    __syncthreads();
    for (int off = 128; off > 0; off >>= 1){
      if (tid < off){ ss[tid] += ss[tid+off]; sq[tid] += sq[tid+off]; }
      __syncthreads();
    }
    if (tid < 16){
      const float mu  = ss[0] * (1.f/16384.f);
      const float var = sq[0] * (1.f/16384.f) - mu*mu;   // biased
      const float rstd = rsqrtf(var + 1e-5f);
      const int ch = g*16 + tid;
      const float sc = rstd * w[ch];
      scs[tid] = sc;
      shs[tid] = bia[ch] - mu * sc;
    }
    __syncthreads();
    // normalize from regs -> LDS (whole group at once)
    #pragma unroll
    for (int i = 0; i < 16; ++i){
      const float sc = scs[i], sh = shs[i];
      s16x4 o;
      o[0]=f2bf(v[i].x*sc+sh); o[1]=f2bf(v[i].y*sc+sh);
      o[2]=f2bf(v[i].z*sc+sh); o[3]=f2bf(v[i].w*sc+sh);
      *(s16x4*)&L[i*1032 + tid*4] = o;
    }
    __syncthreads();
    // transposed write: 8 s16x8 units per thread -> xnT[b][t][g*16..+15]
    short* ob = xnT + (size_t)b * 524288 + g*16;
    #pragma unroll
    for (int u = 0; u < 8; ++u){
      const int unit = tid + u*256;            // 0..2047
      const int t = unit >> 1, c8 = (unit & 1)*8;
      s16x8 o;
      #pragma unroll
      for (int j = 0; j < 8; ++j) o[j] = L[(c8 + j)*1032 + t];
      *(s16x8*)(ob + (size_t)t*512 + c8) = o;
    }
  } else {
    const int i = (blockIdx.x - 256)*256 + tid;   // 0..131071
    const float* in; short* out; float s;
    if (i < 98304){
      in = qkv_w + (size_t)i*8; out = qwb + (size_t)i*8;
      s = (((i >> 6) % 192) < 128) ? QK_SCALE : 1.f;     // q,k rows pre-scaled
    } else {
      const int j = i - 98304;
      in = proj_w + (size_t)j*8; out = pwb + (size_t)j*8;
      s = 1.f;
    }
    const float4* p = (const float4*)in;
    float4 a = p[0], b2 = p[1];
    s16x8 o;
    o[0]=f2bf(a.x*s);  o[1]=f2bf(a.y*s);  o[2]=f2bf(a.z*s);  o[3]=f2bf(a.w*s);
    o[4]=f2bf(b2.x*s); o[5]=f2bf(b2.y*s); o[6]=f2bf(b2.z*s); o[7]=f2bf(b2.w*s);
    *(s16x8*)out = o;
  }
}

// ---------------------------------------------------------------------------
// Unified K=512 GEMM, 128xNB tile, BK=32, 4 waves (2x2).
// Staging: global_load_lds w=16 into linear [row][32] tiles; XOR swizzle
// slot = lb ^ ((row>>1)&3) on reads, source chunk (c&3)^((c>>3)&3) on stage.
// MODE 0 (NB=128, fused QKV), part = z>>2:
//   part 0 (Q), part 1 (K): D[c][t] = W x xnT -> frag-tiles, r-contiguous
//     s16x4 stores.  part 2 (V): D[t][o'] -> vbuf frag-tiles, s16x4 stores.
// MODE 2 (NB=64): A=Wp o-rows, B=attT t-rows -> f32 out via LDS-transposed
//   epilogue: 256B-coalesced float4 resid-add/store (resid hoisted).
template<int MODE, int NB>
__global__ __launch_bounds__(256) void gemm_k512(const short* __restrict__ W,
    const short* __restrict__ act, const float* __restrict__ bias,
    const float* __restrict__ resid, void* __restrict__ outp,
    void* __restrict__ outp2, void* __restrict__ outp3){
  constexpr int NSF = NB / 32;      // n-frags per wave
  constexpr int SMEM_BYTES = (MODE == 2) ? 34816 : 32768;
  const int b  = blockIdx.x;
  const int tid  = threadIdx.x;
  const int lane = tid & 63, w = tid >> 6;
  const int wm = w >> 1, wn = w & 1;
  const int lm = lane & 15, lb = lane >> 4;
  const int xr = (lm >> 1) & 3;     // row-swizzle term for frag reads

  int part, m0, n0;
  if constexpr (MODE == 0){
    const int z = blockIdx.z;
    part = z >> 2;                  // 0=Q 1=K 2=V
    if (part < 2){ m0 = (z & 3)*128; n0 = blockIdx.y*128; }
    else         { m0 = blockIdx.y*128; n0 = 1024 + (z & 3)*128; }
  } else {
    part = 0; m0 = blockIdx.y*128; n0 = blockIdx.z*NB;
  }

  __shared__ __align__(16) char smem[SMEM_BYTES];
  short* Asb = (short*)smem;                 // [2][128*32]
  short* Bsb = (short*)(smem + 16384);       // [2][NB*32]

  const short* actb = act + (size_t)b * 524288;

  auto arow = [&](int r) -> const short* {
    if constexpr (MODE == 0){
      if (part < 2){
        const int m = m0 + r;
        return W + (size_t)(192*(m>>6) + part*64 + (m&63)) * 512;
      }
      return actb + (size_t)(m0 + r) * 512;
    } else {
      return W + (size_t)(m0 + r) * 512;
    }
  };
  auto brow = [&](int r) -> const short* {
    if constexpr (MODE == 0){
      if (part < 2) return actb + (size_t)(n0 + r) * 512;
      const int o = n0 + r;                   // 1024..1535
      return W + (size_t)(192*((o>>6)&7) + 128 + (o&63)) * 512;
    } else {
      return actb + (size_t)(n0 + r) * 512;
    }
  };

  // stage K-tile t into buf: async gload_lds; source chunk pre-swizzled
  auto stage = [&](int t, int buf){
    const int k0 = t * 32;
    #pragma unroll
    for (int i = 0; i < 2; ++i){
      const int c = tid + i*256;
      const int r = c >> 2, sj = (c & 3) ^ ((c >> 3) & 3);
      gload16(arow(r) + k0 + sj*8, Asb + buf*4096 + (c>>2)*32 + (c&3)*8);
    }
    #pragma unroll
    for (int i = 0; i < NB/64; ++i){
      const int c = tid + i*256;
      const int r = c >> 2, sj = (c & 3) ^ ((c >> 3) & 3);
      gload16(brow(r) + k0 + sj*8, Bsb + buf*(NB*32) + (c>>2)*32 + (c&3)*8);
    }
  };

  f32x4 acc[4][NSF] = {};
  stage(0, 0);

  for (int t = 0; t < 16; ++t){
    __syncthreads();                 // waits vmcnt(0) for prior stage
    if (t + 1 < 16) stage(t + 1, (t + 1) & 1);
    const int buf = t & 1;

    s16x8 af[4], bfr[NSF];
    #pragma unroll
    for (int ms = 0; ms < 4; ++ms){
      const int row = wm*64 + ms*16 + lm;
      af[ms] = *(const s16x8*)(Asb + buf*4096 + row*32 + ((lb ^ xr) << 3));
    }
    #pragma unroll
    for (int ns = 0; ns < NSF; ++ns){
      const int row = wn*(NB/2) + ns*16 + lm;
      bfr[ns] = *(const s16x8*)(Bsb + buf*(NB*32) + row*32 + ((lb ^ xr) << 3));
    }
    #pragma unroll
    for (int ns = 0; ns < NSF; ++ns)
      #pragma unroll
      for (int ms = 0; ms < 4; ++ms)
        acc[ms][ns] = mfma_bf16_16x16x32(af[ms], bfr[ns], acc[ms][ns]);
  }

  // C/D: col = lane&15, row = 4*(lane>>4) + reg   (m89)
  const int mo = m0 + wm*64, no = n0 + wn*(NB/2);
  if constexpr (MODE == 0){
    if (part < 2){
      // Q/K in D[c][t] orientation: m = channel, n = t/s; r-contiguous tiles.
      short* outT = (short*)(part == 0 ? outp : outp2) + (size_t)b * 524288;
      const int hh = m0/64 + wm;                           // m>>6, wave-uniform
      float bm[16];
      #pragma unroll
      for (int ms = 0; ms < 4; ++ms)
        #pragma unroll
        for (int r = 0; r < 4; ++r){
          const int m = mo + ms*16 + 4*lb + r;
          bm[ms*4+r] = QK_SCALE * bias[192*(m>>6) + part*64 + (m&63)];
        }
      #pragma unroll
      for (int ms = 0; ms < 4; ++ms)
        #pragma unroll
        for (int ns = 0; ns < NSF; ++ns){
          const int n = no + ns*16 + lm;                   // t (attn s/t)
          const size_t a = ((size_t)hh*128 + (n>>4)*2 + (ms>>1))*512
                         + (((ms*2 + (lb>>1)) & 3)*16 + (n&15))*8 + 4*(lb&1);
          s16x4 o;
          #pragma unroll
          for (int r = 0; r < 4; ++r) o[r] = f2bf(acc[ms][ns][r] + bm[ms*4+r]);
          *(s16x4*)(outT + a) = o;
        }
    } else {
      short* vout = (short*)outp3 + (size_t)b * 524288;    // frag tiles
      float bn[NSF];
      #pragma unroll
      for (int ns = 0; ns < NSF; ++ns){
        const int o = no + ns*16 + lm;
        bn[ns] = bias[192*((o>>6)&7) + 128 + (o&63)];
      }
      #pragma unroll
      for (int ms = 0; ms < 4; ++ms)
        #pragma unroll
        for (int ns = 0; ns < NSF; ++ns){
          const int m = mo + ms*16 + 4*lb;                 // r=0 row; s = m+r
          const int n = no + ns*16 + lm;
          const int h = (n >> 6) & 7, c = n & 63;
          const size_t a = ((size_t)h*128 + (c>>4)*32 + (m>>5))*512
                         + (((m>>2)&3)*16 + (c&15))*8 + ((m>>4)&1)*4;
          s16x4 o;
          #pragma unroll
          for (int r = 0; r < 4; ++r) o[r] = f2bf(acc[ms][ns][r] + bn[ns]);
          *(s16x4*)(vout + a) = o;
        }
    }
  } else {
    // proj: hoist residual loads (resolve under the LDS transpose), then
    // LDS-transposed epilogue -> coalesced float4 store
    const float* xr2 = resid + (size_t)b * 524288;
    float4 rv[8];
    #pragma unroll
    for (int p = 0; p < 8; ++p){
      const int row = p*16 + (tid >> 4);
      rv[p] = *(const float4*)(xr2 + (size_t)(m0 + row)*1024 + n0 + (tid & 15)*4);
    }
    __syncthreads();                          // staging reads done
    float* Lf = (float*)smem;                 // [128][68] f32
    #pragma unroll
    for (int ms = 0; ms < 4; ++ms)
      #pragma unroll
      for (int ns = 0; ns < NSF; ++ns)
        #pragma unroll
        for (int r = 0; r < 4; ++r)
          Lf[(wm*64 + ms*16 + 4*lb + r)*68 + wn*32 + ns*16 + lm] = acc[ms][ns][r];
    __syncthreads();
    float* out = (float*)outp + (size_t)b * 524288;
    #pragma unroll
    for (int p = 0; p < 8; ++p){
      const int row = p*16 + (tid >> 4);
      const int c4  = (tid & 15) * 4;
      float4 v = *(const float4*)&Lf[row*68 + c4];
      const float bs = bias[m0 + row];
      const size_t off = (size_t)(m0 + row)*1024 + n0 + c4;
      float4 ov = make_float4(v.x+bs+rv[p].x, v.y+bs+rv[p].y,
                              v.z+bs+rv[p].z, v.w+bs+rv[p].w);
      *(float4*)(out + off) = ov;
    }
  }
}

// ---------------------------------------------------------------------------
// Attention v12 (R14/R15, unchanged): barrier-free, ONE block per CU. 256
// blocks x 512 thr; bid = bh + 64*tc (bh%8 -> XCD). Wave w owns 32 t-cols of
// a 256-t chunk; all 8 waves share one K/V stream (L1 dedup). Q/K/V frags ALL
// single coalesced 1KB b128 loads. K ping-pong prefetch. exp2 direct (shift-
// invariant, |s|<~10 << 125). lsum as f32x4 (4 indep chains), reduced once.
__global__ __launch_bounds__(512) void attn12_kernel(const short* __restrict__ qbuf,
    const short* __restrict__ kbuf, const short* __restrict__ vbuf,
    short* __restrict__ attT){
  const int bid = blockIdx.x;
  const int bh = bid & 63, tc = bid >> 6;
  const int b = bh >> 3, h = bh & 7;
  const int tid = threadIdx.x;
  const int lane = tid & 63, w = tid >> 6;
  const int lm = lane & 15, lb = lane >> 4;
  const int t0 = tc * 256;

  const short* qb = qbuf + (size_t)b*524288 + (size_t)h*65536 + lane*8;
  const short* kb = kbuf + (size_t)b*524288 + (size_t)h*65536 + lane*8;
  const short* vb = vbuf + (size_t)b*524288 + (size_t)h*65536 + lane*8;

  __shared__ short Tl[256*72];       // epilogue transpose only (36864 B)

  // Q frags: coalesced 1KB tile loads (tile = (t>>4)*2 + ks)
  s16x8 qf[2][2];
  #pragma unroll
  for (int tb = 0; tb < 2; ++tb)
    #pragma unroll
    for (int ks = 0; ks < 2; ++ks)
      qf[tb][ks] = *(const s16x8*)(qb +
          (size_t)((((t0 >> 4) + w*2 + tb)*2) + ks)*512);

  f32x4 of[2][4] = {};
  f32x4 lacc[2] = {};                // 4 independent partial-sum chains per tb
  s16x8 kA[2][4], kB[2][4];

  auto load_k = [&](int it, s16x8 (&kf)[2][4]){
    #pragma unroll
    for (int ks = 0; ks < 2; ++ks)
      #pragma unroll
      for (int ms = 0; ms < 4; ++ms)
        kf[ks][ms] = *(const s16x8*)(kb + (size_t)((it*4 + ms)*2 + ks)*512);
  };

  auto body = [&](int it, s16x8 (&kcur)[2][4], s16x8 (&knxt)[2][4]){
    // V frags for this iter (consumed last -> latency hidden under QK+exp)
    s16x8 vf[2][4];
    #pragma unroll
    for (int ks2 = 0; ks2 < 2; ++ks2)
      #pragma unroll
      for (int cs = 0; cs < 4; ++cs)
        vf[ks2][cs] = *(const s16x8*)(vb + (size_t)(cs*32 + it*2 + ks2)*512);

    // prefetch next iter's K frags (consumed next body -> latency hidden)
    if (it + 1 < 16) load_k(it + 1, knxt);

    // QK^T: S'[s][t]
    f32x4 sf[2][4];
    #pragma unroll
    for (int tb = 0; tb < 2; ++tb)
      #pragma unroll
      for (int ms = 0; ms < 4; ++ms) sf[tb][ms] = 0.f;
    #pragma unroll
    for (int ks = 0; ks < 2; ++ks)
      #pragma unroll
      for (int ms = 0; ms < 4; ++ms){
        sf[0][ms] = mfma_bf16_16x16x32(kcur[ks][ms], qf[0][ks], sf[0][ms]);
        sf[1][ms] = mfma_bf16_16x16x32(kcur[ks][ms], qf[1][ks], sf[1][ms]);
      }

    // p = exp2(s) directly; lsum in 4 independent chains (r-indexed, unrolled)
    s16x8 pbf[2][2];
    #pragma unroll
    for (int tb = 0; tb < 2; ++tb)
      #pragma unroll
      for (int ms = 0; ms < 4; ++ms)
        #pragma unroll
        for (int r = 0; r < 4; ++r){
          const float e = __builtin_amdgcn_exp2f(sf[tb][ms][r]);
          lacc[tb][r] += e;
          pbf[tb][ms >> 1][(ms & 1)*4 + r] = f2bf(e);
        }

    // PV: D[c][t] = mfma(A=V frag, B=P' in-lane)
    #pragma unroll
    for (int ks2 = 0; ks2 < 2; ++ks2)
      #pragma unroll
      for (int cs = 0; cs < 4; ++cs){
        of[0][cs] = mfma_bf16_16x16x32(vf[ks2][cs], pbf[0][ks2], of[0][cs]);
        of[1][cs] = mfma_bf16_16x16x32(vf[ks2][cs], pbf[1][ks2], of[1][cs]);
      }
  };

  load_k(0, kA);
  for (int it2 = 0; it2 < 16; it2 += 2){
    body(it2,     kA, kB);
    body(it2 + 1, kB, kA);
  }

  // reduce partial sums: 4 chains -> scalar, then across the 4 lb groups
  float lsum[2];
  #pragma unroll
  for (int tb = 0; tb < 2; ++tb){
    lsum[tb] = (lacc[tb][0] + lacc[tb][1]) + (lacc[tb][2] + lacc[tb][3]);
    lsum[tb] += __shfl_xor(lsum[tb], 16, 64);
    lsum[tb] += __shfl_xor(lsum[tb], 32, 64);
  }
  const float inv0 = 1.f / lsum[0], inv1 = 1.f / lsum[1];

  // transpose [c][t] regs -> attT[b][t][c] via LDS
  #pragma unroll
  for (int tb = 0; tb < 2; ++tb)
    #pragma unroll
    for (int cs = 0; cs < 4; ++cs){
      s16x4 o;
      #pragma unroll
      for (int r = 0; r < 4; ++r)
        o[r] = f2bf(of[tb][cs][r] * (tb ? inv1 : inv0));
      *(s16x4*)&Tl[(w*32 + tb*16 + lm)*72 + cs*16 + 4*lb] = o;
    }
  __syncthreads();
  short* outb = attT + (size_t)b*524288 + (size_t)t0*512 + h*64;
  #pragma unroll
  for (int i = 0; i < 4; ++i){
    const int g = tid + i*512, r = g >> 3, c8 = g & 7;
    *(uint4*)(outb + (size_t)r*512 + c8*8) = *(const uint4*)&Tl[r*72 + c8*8];
  }
}

// ---------------------------------------------------------------------------
extern "C" void kernel_launch(void* const* d_in, const int* in_sizes, int n_in,
                              void* d_out, int out_size, void* d_ws, size_t ws_size,
                              hipStream_t stream){
  const float* x      = (const float*)d_in[0];
  const float* norm_w = (const float*)d_in[1];
  const float* norm_b = (const float*)d_in[2];
  const float* qkv_w  = (const float*)d_in[3];
  const float* qkv_b  = (const float*)d_in[4];
  const float* proj_w = (const float*)d_in[5];
  const float* proj_b = (const float*)d_in[6];

  char* ws = (char*)d_ws;
  short*  xnT   = (short*)(ws + 4096);              // 8 MiB
  short*  qwb   = (short*)(ws + 8392704);           // 1.5 MiB
  short*  pwb   = (short*)(ws + 9965568);           // 0.5 MiB
  short*  qbuf  = (short*)(ws + 10489856);          // 8 MiB (frag tiles)
  short*  kbuf  = (short*)(ws + 18878464);          // 8 MiB (frag tiles)
  short*  vbuf  = (short*)(ws + 27267072);          // 8 MiB (frag tiles)
  short*  attT  = (short*)(ws + 35655680);          // 8 MiB

  gn_fused_kernel<<<dim3(768), dim3(256), 0, stream>>>(x, norm_w, norm_b, xnT,
      qkv_w, proj_w, qwb, pwb);
  gemm_k512<0,128><<<dim3(8, 8, 12), dim3(256), 0, stream>>>(qwb, xnT, qkv_b, nullptr,
      (void*)qbuf, (void*)kbuf, (void*)vbuf);
  attn12_kernel<<<dim3(256), dim3(512), 0, stream>>>(qbuf, kbuf, vbuf, attT);
  gemm_k512<2,64><<<dim3(8, 4, 16), dim3(256), 0, stream>>>(pwb, attT, proj_b, x,
      d_out, nullptr, nullptr);
}

// Round 17
// 67.983 us; speedup vs baseline: 1.3721x; 1.0072x over previous
//
#include <hip/hip_runtime.h>
#include <stdint.h>

// ---------------------------------------------------------------------------
// AttentionBlock: GroupNorm(32) -> qkv 1x1 -> 8-head attention (T=1024,ch=64)
//                 -> proj 1x1 + residual.  B=8, C=512, T=1024. fp32 I/O,
//                 bf16 MFMA internally.  4 kernels:
//   gn_fused: blocks 0..255 = per-(b,group) stats + normalize + transpose,
//             x reg-resident, wave-shuffle stats reduce (2 barriers total);
//             blocks 256..767 = weight cvt.
//   gemmQKV: fused; Q,K = D[c][t] = W x xnT -> frag-tiles (r-contiguous
//            s16x4 stores); V = D[t][o'] -> frag-tiles (s16x4 stores).
//   attn   : barrier-free flash: 256 blk x 8 waves x 32t, 1 blk/CU, shared
//            K/V stream; BOTH K and V ping-pong prefetched one iter ahead
//            (full-iteration latency cover); Q/K/V frags ALL coalesced 1KB
//            b128 loads; exp2 direct (no max: |s|<~10, shift-invariant);
//            lsum as f32x4 (4 indep add chains).
//   proj   : D[o][t] = Wp x att + bias + x -> d_out; LDS-transposed epilogue
//            with residual loads hoisted before the barrier (T14).
// Frag-tile layout (1KB): addr = tile*512 + lane*8 + j; A/B share slot->k map
//   so the HW k-permutation cancels.
// Lessons: R4 spills; R5 LDS>64K; R7/R12 split adds traffic+load-instrs;
//   R8 strided reads; R9-R14 scattered 2B stores fixed; R13 scheduling null;
//   R15 one-x-pass fusion; R16 reg-resident gn + hoisted proj residual;
//   R17 V-prefetch (attn dependency-chain cover) + shuffle stats reduce.
// ---------------------------------------------------------------------------

typedef float  f32x4  __attribute__((ext_vector_type(4)));
typedef short  s16x4  __attribute__((ext_vector_type(4)));
typedef short  s16x8  __attribute__((ext_vector_type(8)));
typedef __bf16 bf16x8 __attribute__((ext_vector_type(8)));

#define QK_SCALE 0.4246609f   // sqrt(0.125 * log2(e))

__device__ __forceinline__ f32x4 mfma_bf16_16x16x32(s16x8 a, s16x8 b, f32x4 c){
  return __builtin_amdgcn_mfma_f32_16x16x32_bf16(
      __builtin_bit_cast(bf16x8, a), __builtin_bit_cast(bf16x8, b), c, 0, 0, 0);
}

__device__ __forceinline__ short f2bf(float v){
  return __builtin_bit_cast(short, static_cast<__bf16>(v));
}

// async global->LDS, 16B per lane; dest = firstlane-base + lane*16 (linear)
__device__ __forceinline__ void gload16(const void* g, void* l){
  __builtin_amdgcn_global_load_lds(
      (const __attribute__((address_space(1))) void*)g,
      (__attribute__((address_space(3))) void*)l, 16, 0, 0);
}

// ---------------------------------------------------------------------------
// gn_fused: blocks 0..255 = (b,g) stats+normalize+transpose (reg-resident x,
// wave-shuffle stats reduce); blocks 256..767 = weight cvt.
__global__ __launch_bounds__(256) void gn_fused_kernel(const float* __restrict__ x,
    const float* __restrict__ w, const float* __restrict__ bia,
    short* __restrict__ xnT, const float* __restrict__ qkv_w,
    const float* __restrict__ proj_w, short* __restrict__ qwb,
    short* __restrict__ pwb){
  const int tid = threadIdx.x;
  if (blockIdx.x < 256){
    __shared__ float ssw[4], sqw[4];
    __shared__ float scs[16], shs[16];
    __shared__ short L[16*1032];               // [ch][1024 t] pad->1032
    const int bg = blockIdx.x;
    const int b = bg >> 5, g = bg & 31;
    const float* xb = x + (size_t)bg * 16384;  // [16ch][1024t]
    // pass 1: load once, keep in regs, accumulate stats
    float4 v[16];
    float s = 0.f, q = 0.f;
    #pragma unroll
    for (int i = 0; i < 16; ++i){
      v[i] = ((const float4*)xb)[tid + i*256];
      s += v[i].x + v[i].y + v[i].z + v[i].w;
      q += v[i].x*v[i].x + v[i].y*v[i].y + v[i].z*v[i].z + v[i].w*v[i].w;
    }
    // wave-level shuffle reduce (6 levels), then 4-entry LDS combine
    #pragma unroll
    for (int off = 32; off > 0; off >>= 1){
      s += __shfl_xor(s, off, 64);
      q += __shfl_xor(q, off, 64);
    }
    if ((tid & 63) == 0){ ssw[tid >> 6] = s; sqw[tid >> 6] = q; }
    __syncthreads();
    if (tid < 16){
      const float st = (ssw[0] + ssw[1]) + (ssw[2] + ssw[3]);
      const float qt = (sqw[0] + sqw[1]) + (sqw[2] + sqw[3]);
      const float mu  = st * (1.f/16384.f);
      const float var = qt * (1.f/16384.f) - mu*mu;   // biased
      const float rstd = rsqrtf(var + 1e-5f);
      const int ch = g*16 + tid;
      const float sc = rstd * w[ch];
      scs[tid] = sc;
      shs[tid] = bia[ch] - mu * sc;
    }
    __syncthreads();
    // normalize from regs -> LDS (whole group at once)
    #pragma unroll
    for (int i = 0; i < 16; ++i){
      const float sc = scs[i], sh = shs[i];
      s16x4 o;
      o[0]=f2bf(v[i].x*sc+sh); o[1]=f2bf(v[i].y*sc+sh);
      o[2]=f2bf(v[i].z*sc+sh); o[3]=f2bf(v[i].w*sc+sh);
      *(s16x4*)&L[i*1032 + tid*4] = o;
    }
    __syncthreads();
    // transposed write: 8 s16x8 units per thread -> xnT[b][t][g*16..+15]
    short* ob = xnT + (size_t)b * 524288 + g*16;
    #pragma unroll
    for (int u = 0; u < 8; ++u){
      const int unit = tid + u*256;            // 0..2047
      const int t = unit >> 1, c8 = (unit & 1)*8;
      s16x8 o;
      #pragma unroll
      for (int j = 0; j < 8; ++j) o[j] = L[(c8 + j)*1032 + t];
      *(s16x8*)(ob + (size_t)t*512 + c8) = o;
    }
  } else {
    const int i = (blockIdx.x - 256)*256 + tid;   // 0..131071
    const float* in; short* out; float s;
    if (i < 98304){
      in = qkv_w + (size_t)i*8; out = qwb + (size_t)i*8;
      s = (((i >> 6) % 192) < 128) ? QK_SCALE : 1.f;     // q,k rows pre-scaled
    } else {
      const int j = i - 98304;
      in = proj_w + (size_t)j*8; out = pwb + (size_t)j*8;
      s = 1.f;
    }
    const float4* p = (const float4*)in;
    float4 a = p[0], b2 = p[1];
    s16x8 o;
    o[0]=f2bf(a.x*s);  o[1]=f2bf(a.y*s);  o[2]=f2bf(a.z*s);  o[3]=f2bf(a.w*s);
    o[4]=f2bf(b2.x*s); o[5]=f2bf(b2.y*s); o[6]=f2bf(b2.z*s); o[7]=f2bf(b2.w*s);
    *(s16x8*)out = o;
  }
}

// ---------------------------------------------------------------------------
// Unified K=512 GEMM, 128xNB tile, BK=32, 4 waves (2x2).
// Staging: global_load_lds w=16 into linear [row][32] tiles; XOR swizzle
// slot = lb ^ ((row>>1)&3) on reads, source chunk (c&3)^((c>>3)&3) on stage.
// MODE 0 (NB=128, fused QKV), part = z>>2:
//   part 0 (Q), part 1 (K): D[c][t] = W x xnT -> frag-tiles, r-contiguous
//     s16x4 stores.  part 2 (V): D[t][o'] -> vbuf frag-tiles, s16x4 stores.
// MODE 2 (NB=64): A=Wp o-rows, B=attT t-rows -> f32 out via LDS-transposed
//   epilogue: 256B-coalesced float4 resid-add/store (resid hoisted).
template<int MODE, int NB>
__global__ __launch_bounds__(256) void gemm_k512(const short* __restrict__ W,
    const short* __restrict__ act, const float* __restrict__ bias,
    const float* __restrict__ resid, void* __restrict__ outp,
    void* __restrict__ outp2, void* __restrict__ outp3){
  constexpr int NSF = NB / 32;      // n-frags per wave
  constexpr int SMEM_BYTES = (MODE == 2) ? 34816 : 32768;
  const int b  = blockIdx.x;
  const int tid  = threadIdx.x;
  const int lane = tid & 63, w = tid >> 6;
  const int wm = w >> 1, wn = w & 1;
  const int lm = lane & 15, lb = lane >> 4;
  const int xr = (lm >> 1) & 3;     // row-swizzle term for frag reads

  int part, m0, n0;
  if constexpr (MODE == 0){
    const int z = blockIdx.z;
    part = z >> 2;                  // 0=Q 1=K 2=V
    if (part < 2){ m0 = (z & 3)*128; n0 = blockIdx.y*128; }
    else         { m0 = blockIdx.y*128; n0 = 1024 + (z & 3)*128; }
  } else {
    part = 0; m0 = blockIdx.y*128; n0 = blockIdx.z*NB;
  }

  __shared__ __align__(16) char smem[SMEM_BYTES];
  short* Asb = (short*)smem;                 // [2][128*32]
  short* Bsb = (short*)(smem + 16384);       // [2][NB*32]

  const short* actb = act + (size_t)b * 524288;

  auto arow = [&](int r) -> const short* {
    if constexpr (MODE == 0){
      if (part < 2){
        const int m = m0 + r;
        return W + (size_t)(192*(m>>6) + part*64 + (m&63)) * 512;
      }
      return actb + (size_t)(m0 + r) * 512;
    } else {
      return W + (size_t)(m0 + r) * 512;
    }
  };
  auto brow = [&](int r) -> const short* {
    if constexpr (MODE == 0){
      if (part < 2) return actb + (size_t)(n0 + r) * 512;
      const int o = n0 + r;                   // 1024..1535
      return W + (size_t)(192*((o>>6)&7) + 128 + (o&63)) * 512;
    } else {
      return actb + (size_t)(n0 + r) * 512;
    }
  };

  // stage K-tile t into buf: async gload_lds; source chunk pre-swizzled
  auto stage = [&](int t, int buf){
    const int k0 = t * 32;
    #pragma unroll
    for (int i = 0; i < 2; ++i){
      const int c = tid + i*256;
      const int r = c >> 2, sj = (c & 3) ^ ((c >> 3) & 3);
      gload16(arow(r) + k0 + sj*8, Asb + buf*4096 + (c>>2)*32 + (c&3)*8);
    }
    #pragma unroll
    for (int i = 0; i < NB/64; ++i){
      const int c = tid + i*256;
      const int r = c >> 2, sj = (c & 3) ^ ((c >> 3) & 3);
      gload16(brow(r) + k0 + sj*8, Bsb + buf*(NB*32) + (c>>2)*32 + (c&3)*8);
    }
  };

  f32x4 acc[4][NSF] = {};
  stage(0, 0);

  for (int t = 0; t < 16; ++t){
    __syncthreads();                 // waits vmcnt(0) for prior stage
    if (t + 1 < 16) stage(t + 1, (t + 1) & 1);
    const int buf = t & 1;

    s16x8 af[4], bfr[NSF];
    #pragma unroll
    for (int ms = 0; ms < 4; ++ms){
      const int row = wm*64 + ms*16 + lm;
      af[ms] = *(const s16x8*)(Asb + buf*4096 + row*32 + ((lb ^ xr) << 3));
    }
    #pragma unroll
    for (int ns = 0; ns < NSF; ++ns){
      const int row = wn*(NB/2) + ns*16 + lm;
      bfr[ns] = *(const s16x8*)(Bsb + buf*(NB*32) + row*32 + ((lb ^ xr) << 3));
    }
    #pragma unroll
    for (int ns = 0; ns < NSF; ++ns)
      #pragma unroll
      for (int ms = 0; ms < 4; ++ms)
        acc[ms][ns] = mfma_bf16_16x16x32(af[ms], bfr[ns], acc[ms][ns]);
  }

  // C/D: col = lane&15, row = 4*(lane>>4) + reg   (m89)
  const int mo = m0 + wm*64, no = n0 + wn*(NB/2);
  if constexpr (MODE == 0){
    if (part < 2){
      // Q/K in D[c][t] orientation: m = channel, n = t/s; r-contiguous tiles.
      short* outT = (short*)(part == 0 ? outp : outp2) + (size_t)b * 524288;
      const int hh = m0/64 + wm;                           // m>>6, wave-uniform
      float bm[16];
      #pragma unroll
      for (int ms = 0; ms < 4; ++ms)
        #pragma unroll
        for (int r = 0; r < 4; ++r){
          const int m = mo + ms*16 + 4*lb + r;
          bm[ms*4+r] = QK_SCALE * bias[192*(m>>6) + part*64 + (m&63)];
        }
      #pragma unroll
      for (int ms = 0; ms < 4; ++ms)
        #pragma unroll
        for (int ns = 0; ns < NSF; ++ns){
          const int n = no + ns*16 + lm;                   // t (attn s/t)
          const size_t a = ((size_t)hh*128 + (n>>4)*2 + (ms>>1))*512
                         + (((ms*2 + (lb>>1)) & 3)*16 + (n&15))*8 + 4*(lb&1);
          s16x4 o;
          #pragma unroll
          for (int r = 0; r < 4; ++r) o[r] = f2bf(acc[ms][ns][r] + bm[ms*4+r]);
          *(s16x4*)(outT + a) = o;
        }
    } else {
      short* vout = (short*)outp3 + (size_t)b * 524288;    // frag tiles
      float bn[NSF];
      #pragma unroll
      for (int ns = 0; ns < NSF; ++ns){
        const int o = no + ns*16 + lm;
        bn[ns] = bias[192*((o>>6)&7) + 128 + (o&63)];
      }
      #pragma unroll
      for (int ms = 0; ms < 4; ++ms)
        #pragma unroll
        for (int ns = 0; ns < NSF; ++ns){
          const int m = mo + ms*16 + 4*lb;                 // r=0 row; s = m+r
          const int n = no + ns*16 + lm;
          const int h = (n >> 6) & 7, c = n & 63;
          const size_t a = ((size_t)h*128 + (c>>4)*32 + (m>>5))*512
                         + (((m>>2)&3)*16 + (c&15))*8 + ((m>>4)&1)*4;
          s16x4 o;
          #pragma unroll
          for (int r = 0; r < 4; ++r) o[r] = f2bf(acc[ms][ns][r] + bn[ns]);
          *(s16x4*)(vout + a) = o;
        }
    }
  } else {
    // proj: hoist residual loads (resolve under the LDS transpose), then
    // LDS-transposed epilogue -> coalesced float4 store
    const float* xr2 = resid + (size_t)b * 524288;
    float4 rv[8];
    #pragma unroll
    for (int p = 0; p < 8; ++p){
      const int row = p*16 + (tid >> 4);
      rv[p] = *(const float4*)(xr2 + (size_t)(m0 + row)*1024 + n0 + (tid & 15)*4);
    }
    __syncthreads();                          // staging reads done
    float* Lf = (float*)smem;                 // [128][68] f32
    #pragma unroll
    for (int ms = 0; ms < 4; ++ms)
      #pragma unroll
      for (int ns = 0; ns < NSF; ++ns)
        #pragma unroll
        for (int r = 0; r < 4; ++r)
          Lf[(wm*64 + ms*16 + 4*lb + r)*68 + wn*32 + ns*16 + lm] = acc[ms][ns][r];
    __syncthreads();
    float* out = (float*)outp + (size_t)b * 524288;
    #pragma unroll
    for (int p = 0; p < 8; ++p){
      const int row = p*16 + (tid >> 4);
      const int c4  = (tid & 15) * 4;
      float4 v = *(const float4*)&Lf[row*68 + c4];
      const float bs = bias[m0 + row];
      const size_t off = (size_t)(m0 + row)*1024 + n0 + c4;
      float4 ov = make_float4(v.x+bs+rv[p].x, v.y+bs+rv[p].y,
                              v.z+bs+rv[p].z, v.w+bs+rv[p].w);
      *(float4*)(out + off) = ov;
    }
  }
}

// ---------------------------------------------------------------------------
// Attention v13: barrier-free, ONE block per CU. 256 blocks x 512 thr;
// bid = bh + 64*tc (bh%8 -> XCD). Wave w owns 32 t-cols of a 256-t chunk;
// all 8 waves share one K/V stream (L1 dedup). Q/K/V frags ALL single
// coalesced 1KB b128 loads. BOTH K and V ping-pong prefetched one iteration
// ahead (full iteration of latency cover). exp2 direct (shift-invariant,
// |s|<~10 << 125). lsum as f32x4 (4 indep chains), reduced once.
__global__ __launch_bounds__(512) void attn13_kernel(const short* __restrict__ qbuf,
    const short* __restrict__ kbuf, const short* __restrict__ vbuf,
    short* __restrict__ attT){
  const int bid = blockIdx.x;
  const int bh = bid & 63, tc = bid >> 6;
  const int b = bh >> 3, h = bh & 7;
  const int tid = threadIdx.x;
  const int lane = tid & 63, w = tid >> 6;
  const int lm = lane & 15, lb = lane >> 4;
  const int t0 = tc * 256;

  const short* qb = qbuf + (size_t)b*524288 + (size_t)h*65536 + lane*8;
  const short* kb = kbuf + (size_t)b*524288 + (size_t)h*65536 + lane*8;
  const short* vb = vbuf + (size_t)b*524288 + (size_t)h*65536 + lane*8;

  __shared__ short Tl[256*72];       // epilogue transpose only (36864 B)

  // Q frags: coalesced 1KB tile loads (tile = (t>>4)*2 + ks)
  s16x8 qf[2][2];
  #pragma unroll
  for (int tb = 0; tb < 2; ++tb)
    #pragma unroll
    for (int ks = 0; ks < 2; ++ks)
      qf[tb][ks] = *(const s16x8*)(qb +
          (size_t)((((t0 >> 4) + w*2 + tb)*2) + ks)*512);

  f32x4 of[2][4] = {};
  f32x4 lacc[2] = {};                // 4 independent partial-sum chains per tb
  s16x8 kA[2][4], kB[2][4], vA[2][4], vB[2][4];

  auto load_k = [&](int it, s16x8 (&kf)[2][4]){
    #pragma unroll
    for (int ks = 0; ks < 2; ++ks)
      #pragma unroll
      for (int ms = 0; ms < 4; ++ms)
        kf[ks][ms] = *(const s16x8*)(kb + (size_t)((it*4 + ms)*2 + ks)*512);
  };
  auto load_v = [&](int it, s16x8 (&vf)[2][4]){
    #pragma unroll
    for (int ks2 = 0; ks2 < 2; ++ks2)
      #pragma unroll
      for (int cs = 0; cs < 4; ++cs)
        vf[ks2][cs] = *(const s16x8*)(vb + (size_t)(cs*32 + it*2 + ks2)*512);
  };

  auto body = [&](int it, s16x8 (&kcur)[2][4], s16x8 (&vcur)[2][4],
                  s16x8 (&knxt)[2][4], s16x8 (&vnxt)[2][4]){
    // issue ALL of iter it+1's loads before consuming iter it (latency cover)
    if (it + 1 < 16){ load_k(it + 1, knxt); load_v(it + 1, vnxt); }

    // QK^T: S'[s][t]
    f32x4 sf[2][4];
    #pragma unroll
    for (int tb = 0; tb < 2; ++tb)
      #pragma unroll
      for (int ms = 0; ms < 4; ++ms) sf[tb][ms] = 0.f;
    #pragma unroll
    for (int ks = 0; ks < 2; ++ks)
      #pragma unroll
      for (int ms = 0; ms < 4; ++ms){
        sf[0][ms] = mfma_bf16_16x16x32(kcur[ks][ms], qf[0][ks], sf[0][ms]);
        sf[1][ms] = mfma_bf16_16x16x32(kcur[ks][ms], qf[1][ks], sf[1][ms]);
      }

    // p = exp2(s) directly; lsum in 4 independent chains (r-indexed, unrolled)
    s16x8 pbf[2][2];
    #pragma unroll
    for (int tb = 0; tb < 2; ++tb)
      #pragma unroll
      for (int ms = 0; ms < 4; ++ms)
        #pragma unroll
        for (int r = 0; r < 4; ++r){
          const float e = __builtin_amdgcn_exp2f(sf[tb][ms][r]);
          lacc[tb][r] += e;
          pbf[tb][ms >> 1][(ms & 1)*4 + r] = f2bf(e);
        }

    // PV: D[c][t] = mfma(A=V frag, B=P' in-lane)
    #pragma unroll
    for (int ks2 = 0; ks2 < 2; ++ks2)
      #pragma unroll
      for (int cs = 0; cs < 4; ++cs){
        of[0][cs] = mfma_bf16_16x16x32(vcur[ks2][cs], pbf[0][ks2], of[0][cs]);
        of[1][cs] = mfma_bf16_16x16x32(vcur[ks2][cs], pbf[1][ks2], of[1][cs]);
      }
  };

  load_k(0, kA);
  load_v(0, vA);
  for (int it2 = 0; it2 < 16; it2 += 2){
    body(it2,     kA, vA, kB, vB);
    body(it2 + 1, kB, vB, kA, vA);
  }

  // reduce partial sums: 4 chains -> scalar, then across the 4 lb groups
  float lsum[2];
  #pragma unroll
  for (int tb = 0; tb < 2; ++tb){
    lsum[tb] = (lacc[tb][0] + lacc[tb][1]) + (lacc[tb][2] + lacc[tb][3]);
    lsum[tb] += __shfl_xor(lsum[tb], 16, 64);
    lsum[tb] += __shfl_xor(lsum[tb], 32, 64);
  }
  const float inv0 = 1.f / lsum[0], inv1 = 1.f / lsum[1];

  // transpose [c][t] regs -> attT[b][t][c] via LDS
  #pragma unroll
  for (int tb = 0; tb < 2; ++tb)
    #pragma unroll
    for (int cs = 0; cs < 4; ++cs){
      s16x4 o;
      #pragma unroll
      for (int r = 0; r < 4; ++r)
        o[r] = f2bf(of[tb][cs][r] * (tb ? inv1 : inv0));
      *(s16x4*)&Tl[(w*32 + tb*16 + lm)*72 + cs*16 + 4*lb] = o;
    }
  __syncthreads();
  short* outb = attT + (size_t)b*524288 + (size_t)t0*512 + h*64;
  #pragma unroll
  for (int i = 0; i < 4; ++i){
    const int g = tid + i*512, r = g >> 3, c8 = g & 7;
    *(uint4*)(outb + (size_t)r*512 + c8*8) = *(const uint4*)&Tl[r*72 + c8*8];
  }
}

// ---------------------------------------------------------------------------
extern "C" void kernel_launch(void* const* d_in, const int* in_sizes, int n_in,
                              void* d_out, int out_size, void* d_ws, size_t ws_size,
                              hipStream_t stream){
  const float* x      = (const float*)d_in[0];
  const float* norm_w = (const float*)d_in[1];
  const float* norm_b = (const float*)d_in[2];
  const float* qkv_w  = (const float*)d_in[3];
  const float* qkv_b  = (const float*)d_in[4];
  const float* proj_w = (const float*)d_in[5];
  const float* proj_b = (const float*)d_in[6];

  char* ws = (char*)d_ws;
  short*  xnT   = (short*)(ws + 4096);              // 8 MiB
  short*  qwb   = (short*)(ws + 8392704);           // 1.5 MiB
  short*  pwb   = (short*)(ws + 9965568);           // 0.5 MiB
  short*  qbuf  = (short*)(ws + 10489856);          // 8 MiB (frag tiles)
  short*  kbuf  = (short*)(ws + 18878464);          // 8 MiB (frag tiles)
  short*  vbuf  = (short*)(ws + 27267072);          // 8 MiB (frag tiles)
  short*  attT  = (short*)(ws + 35655680);          // 8 MiB

  gn_fused_kernel<<<dim3(768), dim3(256), 0, stream>>>(x, norm_w, norm_b, xnT,
      qkv_w, proj_w, qwb, pwb);
  gemm_k512<0,128><<<dim3(8, 8, 12), dim3(256), 0, stream>>>(qwb, xnT, qkv_b, nullptr,
      (void*)qbuf, (void*)kbuf, (void*)vbuf);
  attn13_kernel<<<dim3(256), dim3(512), 0, stream>>>(qbuf, kbuf, vbuf, attT);
  gemm_k512<2,64><<<dim3(8, 4, 16), dim3(256), 0, stream>>>(pwb, attT, proj_b, x,
      d_out, nullptr, nullptr);
}